// Round 1
// 926.448 us; speedup vs baseline: 1.0167x; 1.0167x over previous
//
#include <hip/hip_runtime.h>

// MinimalRNNCell h_t = x_t W + h_{t-1} R.  B=32 T=1024 D=512 U=1024, out fp32.
// R4: 2-phase double-buffered LDS pipeline (T3-minimum): stage tile t+1 BEFORE
// computing tile t, one drain+barrier per tile. All-bf16 GEMM path everywhere;
// x is pre-converted to bf16 (Xb, scratch in d_out) so P0 uses the fast
// global_load_lds path instead of the fp32 convert path. 29 launches total.
//   C0: Xb = bf16(x)                       [elementwise, ~96 MB traffic]
//   P0: XW = Xb@W -> XWL (bf16)
//   P1: in-place local scans slot j=1..7   [7 launches, M=4096]
//   P2: KS over 128 chunk carries          [7 launches, M=4096, ping-pong S0/S1]
//   P3: out = L_j + S_{c-1} R^{j+1}        [1 launch, z=8, fp32 out]

typedef __attribute__((ext_vector_type(4))) float  floatx4;
typedef __attribute__((ext_vector_type(4))) float  float4v;
typedef __attribute__((ext_vector_type(8))) short  short8v;
typedef __attribute__((ext_vector_type(4))) short  short4v;

__device__ __forceinline__ short f2bf(float f) {  // RNE
  unsigned u = __float_as_uint(f);
  u += 0x7fffu + ((u >> 16) & 1u);
  return (short)(u >> 16);
}
__device__ __forceinline__ float bf2f(unsigned short u) {
  return __uint_as_float((unsigned)u << 16);
}
__device__ __forceinline__ void ld16(short* lds, const void* g) {  // async 16B global->LDS
  __builtin_amdgcn_global_load_lds((const __attribute__((address_space(1))) unsigned*)g,
                                   (__attribute__((address_space(3))) unsigned*)lds, 16, 0, 0);
}

// row m -> element offset base + z*zs + (m/div)*s1 + (m%div)*s2 ; row valid iff (m/div)>=qmin
struct Addr { long base, s1, s2; int div, qmin; };
struct Op { const void* p[8]; Addr a; long zs; };

// ---------------------------------------------------------------------------
// OUT[z][m,n] = (HASD ? D : 0) + A[m,:]*B  ; N=1024, BN=128, BK=64.
// A bf16 [m][K] via Addr, B bf16 [n][K], D bf16, OUT fp32/bf16.
// M % BM == 0 guaranteed by caller.
// 2-phase pipeline: LDS double-buffered; next tile's global_load_lds issued
// before current tile's ds_read+MFMA; single __syncthreads (vmcnt drain +
// barrier) per tile covers both "next buffer landed" and "all waves done
// reading current buffer".
// ---------------------------------------------------------------------------
template<int BM, bool OF32, bool HASD>
__global__ __launch_bounds__(256) void gemm_k(Op A, Op B, Op D, Op O, int M, int K,
                                              const unsigned short* zbuf)
{
  constexpr int BK = 64;
  constexpr int MF = BM / 32;          // 16x16 m-frags per wave (WM=2)
  constexpr int NF = 4;                // n-frags per wave (WN=2)
  constexpr int ABR = BM / 32;         // A staging rounds (32 rows / round)

  __shared__ __align__(16) short As[2][BM * BK];
  __shared__ __align__(16) short Bs[2][128 * BK];

  const int tid  = threadIdx.x;
  const int lane = tid & 63;
  const int wave = tid >> 6;
  const int wr = wave >> 1, wc = wave & 1;
  const int lm  = lane & 15;
  const int kof = (lane >> 4) * 8;

  const int z   = blockIdx.z;
  const int bm0 = blockIdx.x * BM;     // M-tiles on x -> N-group of one M-tile shares XCD
  const int bn0 = blockIdx.y * 128;

  const long abase = A.a.base + (long)z * A.zs;

  // B staging pointers: 4 rounds x 32 rows, 8 lanes/row (16B each)
  const unsigned short* Bp = (const unsigned short*)B.p[z];
  const unsigned short* bgp[4];
#pragma unroll
  for (int r = 0; r < 4; ++r)
    bgp[r] = Bp + (long)(bn0 + r * 32 + tid / 8) * K + (tid % 8) * 8;

  // A staging pointers: ABR rounds x 32 rows; invalid rows read zbuf (zeros)
  const unsigned short* agp[ABR];
#pragma unroll
  for (int r = 0; r < ABR; ++r) {
    int m = bm0 + r * 32 + tid / 8;
    int q = m / A.a.div;
    long off = abase + (long)q * A.a.s1 + (long)(m % A.a.div) * A.a.s2 + (tid % 8) * 8;
    agp[r] = (q >= A.a.qmin) ? (const unsigned short*)A.p[z] + off
                             : zbuf + (tid % 8) * 8;   // zbuf covers K elems of zeros
  }

  floatx4 acc[MF][NF] = {};

  const int NT = K / BK;

  auto stage = [&](int buf, int kb) {
#pragma unroll
    for (int r = 0; r < ABR; ++r)
      ld16(&As[buf][r * 2048 + tid * 8], agp[r] + kb);
#pragma unroll
    for (int r = 0; r < 4; ++r)
      ld16(&Bs[buf][r * 2048 + tid * 8], bgp[r] + kb);
  };

  // prologue: fill buffer 0
  stage(0, 0);
  __syncthreads();

  int cur = 0;
  for (int t = 0; t < NT; ++t) {
    if (t + 1 < NT) stage(cur ^ 1, (t + 1) * BK);   // issue-ahead: overlaps with MFMA below
#pragma unroll
    for (int ks = 0; ks < 2; ++ks) {
      short8v af[MF], bfr[NF];
#pragma unroll
      for (int i = 0; i < MF; ++i)
        af[i] = *(const short8v*)&As[cur][(wr * MF * 16 + i * 16 + lm) * BK + ks * 32 + kof];
#pragma unroll
      for (int j = 0; j < NF; ++j)
        bfr[j] = *(const short8v*)&Bs[cur][(wc * 64 + j * 16 + lm) * BK + ks * 32 + kof];
#pragma unroll
      for (int i = 0; i < MF; ++i)
#pragma unroll
        for (int j = 0; j < NF; ++j)
          acc[i][j] = __builtin_amdgcn_mfma_f32_16x16x32_bf16(af[i], bfr[j], acc[i][j], 0, 0, 0);
    }
    __syncthreads();   // drains next-tile loads (overlapped) + read-done for cur
    cur ^= 1;
  }

  const long obase = O.a.base + (long)z * O.zs;
  long dbase = 0; const unsigned short* Dp = nullptr;
  if constexpr (HASD) { dbase = D.a.base + (long)z * D.zs; Dp = (const unsigned short*)D.p[z]; }

#pragma unroll
  for (int i = 0; i < MF; ++i) {
#pragma unroll
    for (int r = 0; r < 4; ++r) {
      int m = bm0 + wr * MF * 16 + i * 16 + (lane >> 4) * 4 + r;  // C/D: row=(lane>>4)*4+reg
      long ob = obase + (long)(m / O.a.div) * O.a.s1 + (long)(m % O.a.div) * O.a.s2;
      long db = 0;
      if constexpr (HASD) db = dbase + (long)(m / D.a.div) * D.a.s1 + (long)(m % D.a.div) * D.a.s2;
#pragma unroll
      for (int j = 0; j < NF; ++j) {
        int n = bn0 + wc * 64 + j * 16 + lm;
        float v = acc[i][j][r];
        if constexpr (HASD) v += bf2f(Dp[db + n]);
        if constexpr (OF32) ((float*)O.p[z])[ob + n] = v;
        else ((unsigned short*)O.p[z])[ob + n] = (unsigned short)f2bf(v);
      }
    }
  }
}

// --- converts ----------------------------------------------------------------
__global__ void convert_x(const float* x, unsigned short* Xb) {  // 16.8M elems, 8/thread
  long i = ((long)blockIdx.x * 256 + threadIdx.x) * 8;
  float4v a = *(const float4v*)(x + i);
  float4v b = *(const float4v*)(x + i + 4);
  short8v s;
  s[0] = f2bf(a.x); s[1] = f2bf(a.y); s[2] = f2bf(a.z); s[3] = f2bf(a.w);
  s[4] = f2bf(b.x); s[5] = f2bf(b.y); s[6] = f2bf(b.z); s[7] = f2bf(b.w);
  *(short8v*)(Xb + i) = s;
}
__global__ void convert_wt(const float* W, unsigned short* Wt) {  // Wt[1024][512]
  int i = blockIdx.x * 256 + threadIdx.x;
  int n = i >> 9, k = i & 511;
  Wt[i] = (unsigned short)f2bf(W[(long)k * 1024 + n]);
}
__global__ void convert_rrm(const float* R, unsigned short* Rrm) {
  int i = blockIdx.x * 256 + threadIdx.x;
  Rrm[i] = (unsigned short)f2bf(R[i]);
}
__global__ void convert_rt(const float* R, unsigned short* Rt) {  // Rt[n][k]=R[k][n]
  int i = blockIdx.x * 256 + threadIdx.x;
  int n = i >> 10, k = i & 1023;
  Rt[i] = (unsigned short)f2bf(R[(long)k * 1024 + n]);
}

// --- host helpers ------------------------------------------------------------
static inline Op opS(const void* p, Addr a, long zs = 0) {
  Op o{}; for (int i = 0; i < 8; ++i) o.p[i] = p; o.a = a; o.zs = zs; return o;
}
static inline Addr contig(long base, long stride, int qmin = 0) {
  return Addr{base, stride, 0, 1, qmin};
}

template<int BM, bool OF32, bool HASD>
static inline void G(hipStream_t s, int M, int K, Op A, Op B, Op D, Op O,
                     const unsigned short* zbuf, int Z = 1) {
  dim3 grid(M / BM, 8, Z);
  hipLaunchKernelGGL((gemm_k<BM, OF32, HASD>), grid, dim3(256), 0, s,
                     A, B, D, O, M, K, zbuf);
}

extern "C" void kernel_launch(void* const* d_in, const int* in_sizes, int n_in,
                              void* d_out, int out_size, void* d_ws, size_t ws_size,
                              hipStream_t stream) {
  (void)in_sizes; (void)n_in; (void)out_size; (void)ws_size;
  const float* x = (const float*)d_in[0];     // [32,1024,512]
  const float* W = (const float*)d_in[2];     // [512,1024]
  const float* R = (const float*)d_in[3];     // [1024,1024]
  float* out = (float*)d_out;                 // [32,1024,1024]

  char* ws = (char*)d_ws;
  size_t off = 0;
  auto alloc = [&](size_t bytes) { void* p = ws + off; off += bytes; return p; };
  unsigned short* zbuf = (unsigned short*)alloc(4096);            // >= K elems of zeros
  unsigned short* Wt = (unsigned short*)alloc(1024 * 512 * 2);
  auto mat = [&]() { return (unsigned short*)alloc(1024 * 1024 * 2); };
  unsigned short *Rt = mat(), *Rrm = mat();
  unsigned short *G2 = mat(), *R2 = mat(), *G3 = mat(), *G4 = mat(), *R4 = mat();
  unsigned short *G5 = mat(), *G6 = mat(), *G7 = mat(), *G8 = mat(), *R8 = mat();
  unsigned short *G16 = mat(), *R16 = mat(), *G32 = mat(), *R32 = mat();
  unsigned short *G64 = mat(), *R64 = mat(), *G128 = mat(), *R128 = mat();
  unsigned short *G256 = mat(), *R256 = mat(), *G512 = mat();
  unsigned short* XWL = (unsigned short*)alloc((size_t)32 * 1024 * 1024 * 2);  // [b][t][u] bf16
  unsigned short* S0  = (unsigned short*)alloc((size_t)4096 * 1024 * 2);       // [c*32+b][u]
  unsigned short* S1  = (unsigned short*)alloc((size_t)4096 * 1024 * 2);
  // Xb (bf16 x, 32 MB) lives in the head of d_out: read only by P0, and P3
  // overwrites the whole output at the end.
  unsigned short* Xb = (unsigned short*)d_out;

  const Addr nil{0, 0, 0, 1, 0};
  const Addr c1024{0, 1024, 0, 1, 0};

  hipMemsetAsync(zbuf, 0, 4096, stream);
  hipLaunchKernelGGL(convert_x,   dim3(8192), dim3(256), 0, stream, x, Xb);
  hipLaunchKernelGGL(convert_wt,  dim3(2048), dim3(256), 0, stream, W, Wt);
  hipLaunchKernelGGL(convert_rrm, dim3(4096), dim3(256), 0, stream, R, Rrm);
  hipLaunchKernelGGL(convert_rt,  dim3(4096), dim3(256), 0, stream, R, Rt);

  // power layers: O_z = A_z * B_z (Bt = transposed operand), z-batched
  auto PL = [&](int n, const unsigned short* const* Aa, const unsigned short* const* Bb,
                unsigned short* const* Oo) {
    Op A{}, B{}, D{}, O{};
    A.a = c1024; O.a = c1024; B.a = nil; D.a = nil;
    for (int i = 0; i < n; ++i) { A.p[i] = Aa[i]; B.p[i] = Bb[i]; O.p[i] = Oo[i]; }
    dim3 grid(1024 / 64, 8, n);
    hipLaunchKernelGGL((gemm_k<64, false, false>), grid, dim3(256), 0, stream,
                       A, B, D, O, 1024, 1024, zbuf);
  };
  { const unsigned short* Aa[] = {Rt, Rrm};                 const unsigned short* Bb[] = {Rrm, Rt};
    unsigned short* Oo[] = {G2, R2};                        PL(2, Aa, Bb, Oo); }
  { const unsigned short* Aa[] = {G2, R2, G2};              const unsigned short* Bb[] = {R2, G2, Rrm};
    unsigned short* Oo[] = {G4, R4, G3};                    PL(3, Aa, Bb, Oo); }
  { const unsigned short* Aa[] = {G4, R4, G4, G4, G3};      const unsigned short* Bb[] = {R4, G4, Rrm, R2, R4};
    unsigned short* Oo[] = {G8, R8, G5, G6, G7};            PL(5, Aa, Bb, Oo); }
  { const unsigned short* Aa[] = {G8, R8};                  const unsigned short* Bb[] = {R8, G8};
    unsigned short* Oo[] = {G16, R16};                      PL(2, Aa, Bb, Oo); }
  { const unsigned short* Aa[] = {G16, R16};                const unsigned short* Bb[] = {R16, G16};
    unsigned short* Oo[] = {G32, R32};                      PL(2, Aa, Bb, Oo); }
  { const unsigned short* Aa[] = {G32, R32};                const unsigned short* Bb[] = {R32, G32};
    unsigned short* Oo[] = {G64, R64};                      PL(2, Aa, Bb, Oo); }
  { const unsigned short* Aa[] = {G64, R64};                const unsigned short* Bb[] = {R64, G64};
    unsigned short* Oo[] = {G128, R128};                    PL(2, Aa, Bb, Oo); }
  { const unsigned short* Aa[] = {G128, R128};              const unsigned short* Bb[] = {R128, G128};
    unsigned short* Oo[] = {G256, R256};                    PL(2, Aa, Bb, Oo); }
  { const unsigned short* Aa[] = {G256};                    const unsigned short* Bb[] = {R256};
    unsigned short* Oo[] = {G512};                          PL(1, Aa, Bb, Oo); }

  // P0: XWL = Xb @ W (bf16 in, bf16 out), M=32768 K=512
  G<128, false, false>(stream, 32768, 512,
      opS(Xb, contig(0, 512)), opS(Wt, nil), opS(nullptr, nil), opS(XWL, c1024), zbuf);

  // P1: in-place local scans over slots j (rows m=c*32+b)
  for (int j = 1; j <= 7; ++j) {
    Addr prev{(long)(j - 1) * 1024, 8192, 1048576, 32, 0};
    Addr cur {(long)j * 1024, 8192, 1048576, 32, 0};
    G<64, false, true>(stream, 4096, 1024,
        opS(XWL, prev), opS(Rt, nil), opS(XWL, cur), opS(XWL, cur), zbuf);
  }

  // P2: Kogge-Stone inclusive scan of E_c with operator R^8 (7 steps, ping-pong)
  // s=0: S0[c] = E_c + E_{c-1} R^8   (E_c = XWL slot c*8+7)
  G<64, false, true>(stream, 4096, 1024,
      opS(XWL, Addr{7168 - 8192, 8192, 1048576, 32, 1}), opS(G8, nil),
      opS(XWL, Addr{7168, 8192, 1048576, 32, 0}), opS(S0, c1024), zbuf);
  { const unsigned short* ops[6] = {G16, G32, G64, G128, G256, G512};
    unsigned short* buf[2] = {S0, S1};
    for (int s = 1; s <= 6; ++s) {
      unsigned short* Sp = buf[(s + 1) & 1];   // s=1: S0 -> S1, s=2: S1 -> S0, ...
      unsigned short* Sn = buf[s & 1];
      G<64, false, true>(stream, 4096, 1024,
          opS(Sp, contig(-(32768L << s), 1024, 32 << s)), opS(ops[s - 1], nil),
          opS(Sp, c1024), opS(Sn, c1024), zbuf);
    }
  }
  // final inclusive scan in S0 (after s=6); carry into chunk c is S0[c-1]

  // P3: out[b][c*8+j] = L_j[c,b] + S_{c-1} @ R^{j+1}  (z=j, fp32 out)
  {
    Op B{}; B.a = nil;
    const unsigned short* gj[8] = {Rt, G2, G3, G4, G5, G6, G7, G8};
    for (int i = 0; i < 8; ++i) B.p[i] = gj[i];
    Addr slot{0, 8192, 1048576, 32, 0};
    G<64, true, true>(stream, 4096, 1024,
        opS(S0, contig(-32768, 1024, 32)), B,
        opS(XWL, slot, 1024), opS(out, slot, 1024), zbuf, 8);
  }
}

// Round 2
// 866.015 us; speedup vs baseline: 1.0876x; 1.0698x over previous
//
#include <hip/hip_runtime.h>

// MinimalRNNCell h_t = x_t W + h_{t-1} R.  B=32 T=1024 D=512 U=1024, out fp32.
// R5: depth-3 LDS pipeline with counted vmcnt (T3/T4) + st-style XOR swizzle
// (T2, applied as inverse-swizzled GLOBAL source + swizzled ds_read: rule #21)
// + setprio around MFMA (T5). Uniform BM=64 for all GEMM launches.
//   C0: Xb = bf16(x)                       [elementwise]
//   P0: XW = Xb@W -> XWL (bf16)            [M=32768 K=512]
//   P1: in-place local scans slot j=1..7   [7 launches, M=4096]
//   P2: KS over 128 chunk carries          [7 launches, M=4096, ping-pong S0/S1]
//   P3: out = L_j + S_{c-1} R^{j+1}        [1 launch, z=8, fp32 out]

typedef __attribute__((ext_vector_type(4))) float  floatx4;
typedef __attribute__((ext_vector_type(4))) float  float4v;
typedef __attribute__((ext_vector_type(8))) short  short8v;

__device__ __forceinline__ short f2bf(float f) {  // RNE
  unsigned u = __float_as_uint(f);
  u += 0x7fffu + ((u >> 16) & 1u);
  return (short)(u >> 16);
}
__device__ __forceinline__ float bf2f(unsigned short u) {
  return __uint_as_float((unsigned)u << 16);
}
__device__ __forceinline__ void ld16(short* lds, const void* g) {  // async 16B global->LDS
  __builtin_amdgcn_global_load_lds((const __attribute__((address_space(1))) unsigned*)g,
                                   (__attribute__((address_space(3))) unsigned*)lds, 16, 0, 0);
}

#define WAITV6 asm volatile("s_waitcnt vmcnt(6)" ::: "memory")
#define WAITV8 asm volatile("s_waitcnt vmcnt(8)" ::: "memory")
#define WAITV0 asm volatile("s_waitcnt vmcnt(0)" ::: "memory")

// row m -> element offset base + z*zs + (m/div)*s1 + (m%div)*s2 ; row valid iff (m/div)>=qmin
struct Addr { long base, s1, s2; int div, qmin; };
struct Op { const void* p[8]; Addr a; long zs; };

// ---------------------------------------------------------------------------
// OUT[z][m,n] = (HASD ? D : 0) + A[m,:]*B  ; N=1024, BN=128, BK=64.
// A bf16 [m][K] via Addr, B bf16 [n][K], D bf16, OUT fp32/bf16.
// LDS layout: rows of 64 bf16 (8 slots x 16B); physical slot p of row r holds
// logical slot p ^ (r&7). Staged via linear-dest global_load_lds with the
// inverse swizzle baked into the per-lane GLOBAL address; ds_read applies the
// same XOR. 3-deep pipeline: tile t+2 staged during compute of tile t;
// vmcnt(LPS) (counted, never 0 mid-loop) + raw s_barrier per tile.
// ---------------------------------------------------------------------------
template<int BM, bool OF32, bool HASD>
__global__ __launch_bounds__(256) void gemm_k(Op A, Op B, Op D, Op O, int M, int K,
                                              const unsigned short* zbuf)
{
  constexpr int BK = 64;
  constexpr int MF = BM / 32;          // 16x16 m-frags per wave (WM=2)
  constexpr int NF = 4;                // n-frags per wave (WN=2)
  constexpr int ABR = BM / 32;         // A staging rounds (32 rows / round)
  constexpr int LPS = ABR + 4;         // global_load_lds per thread per stage

  __shared__ __align__(16) short As[3][BM * BK];
  __shared__ __align__(16) short Bs[3][128 * BK];

  const int tid  = threadIdx.x;
  const int lane = tid & 63;
  const int wave = tid >> 6;
  const int wr = wave >> 1, wc = wave & 1;
  const int lm  = lane & 15;
  const int e7  = lm & 7;              // row&7 for all fragment rows this lane reads
  const int grp = lane >> 4;           // 16B column group

  const int z   = blockIdx.z;
  const int bm0 = blockIdx.x * BM;
  const int bn0 = blockIdx.y * 128;

  const long abase = A.a.base + (long)z * A.zs;

  // swizzled source column (elements): physical slot tid%8 of LDS row (tid/8)
  // must hold logical slot (tid%8)^((tid/8)&7)
  const int sw = (((tid & 7) ^ ((tid >> 3) & 7)) << 3);

  // B staging pointers: 4 rounds x 32 rows, 8 lanes/row (16B each)
  const unsigned short* Bp = (const unsigned short*)B.p[z];
  const unsigned short* bgp[4];
#pragma unroll
  for (int r = 0; r < 4; ++r)
    bgp[r] = Bp + (long)(bn0 + r * 32 + tid / 8) * K + sw;

  // A staging pointers: ABR rounds x 32 rows; invalid rows read zbuf (zeros)
  const unsigned short* agp[ABR];
#pragma unroll
  for (int r = 0; r < ABR; ++r) {
    int m = bm0 + r * 32 + tid / 8;
    int q = m / A.a.div;
    long off = abase + (long)q * A.a.s1 + (long)(m % A.a.div) * A.a.s2 + sw;
    agp[r] = (q >= A.a.qmin) ? (const unsigned short*)A.p[z] + off
                             : zbuf + sw;   // zbuf covers K elems of zeros
  }

  floatx4 acc[MF][NF] = {};

  const int NT = K / BK;

  auto stage = [&](int buf, int kb) {
#pragma unroll
    for (int r = 0; r < ABR; ++r)
      ld16(&As[buf][r * 2048 + tid * 8], agp[r] + kb);
#pragma unroll
    for (int r = 0; r < 4; ++r)
      ld16(&Bs[buf][r * 2048 + tid * 8], bgp[r] + kb);
  };

  // prologue: stage tiles 0 and 1; wait tile 0 only (tile 1 stays in flight)
  stage(0, 0);
  if (NT > 1) {
    stage(1, BK);
    if constexpr (LPS == 6) WAITV6; else WAITV8;
  } else {
    WAITV0;
  }
  __builtin_amdgcn_s_barrier();

  int cur = 0;
  for (int t = 0; t < NT; ++t) {
    int nb = cur + 2; if (nb >= 3) nb -= 3;
    if (t + 2 < NT) stage(nb, (t + 2) * BK);   // overlaps with compute below
#pragma unroll
    for (int ks = 0; ks < 2; ++ks) {
      short8v af[MF], bfr[NF];
#pragma unroll
      for (int i = 0; i < MF; ++i) {
        int ar = wr * MF * 16 + i * 16 + lm;
        int ps = ((((ks << 2) | grp) ^ e7) << 3);
        af[i] = *(const short8v*)&As[cur][ar * BK + ps];
      }
#pragma unroll
      for (int j = 0; j < NF; ++j) {
        int br = wc * 64 + j * 16 + lm;
        int ps = ((((ks << 2) | grp) ^ e7) << 3);
        bfr[j] = *(const short8v*)&Bs[cur][br * BK + ps];
      }
      __builtin_amdgcn_s_setprio(1);
#pragma unroll
      for (int i = 0; i < MF; ++i)
#pragma unroll
        for (int j = 0; j < NF; ++j)
          acc[i][j] = __builtin_amdgcn_mfma_f32_16x16x32_bf16(af[i], bfr[j], acc[i][j], 0, 0, 0);
      __builtin_amdgcn_s_setprio(0);
    }
    if (t + 1 < NT) {
      // tile t+1 must be resident for all waves; keep tile t+2's LPS loads in flight
      if (t + 2 < NT) { if constexpr (LPS == 6) WAITV6; else WAITV8; }
      else WAITV0;
      __builtin_amdgcn_s_barrier();   // also fences buf[(t)%3] reuse by next stage
    }
    cur = (cur == 2) ? 0 : cur + 1;
  }

  const long obase = O.a.base + (long)z * O.zs;
  long dbase = 0; const unsigned short* Dp = nullptr;
  if constexpr (HASD) { dbase = D.a.base + (long)z * D.zs; Dp = (const unsigned short*)D.p[z]; }

#pragma unroll
  for (int i = 0; i < MF; ++i) {
#pragma unroll
    for (int r = 0; r < 4; ++r) {
      int m = bm0 + wr * MF * 16 + i * 16 + (lane >> 4) * 4 + r;  // C/D: row=(lane>>4)*4+reg
      long ob = obase + (long)(m / O.a.div) * O.a.s1 + (long)(m % O.a.div) * O.a.s2;
      long db = 0;
      if constexpr (HASD) db = dbase + (long)(m / D.a.div) * D.a.s1 + (long)(m % D.a.div) * D.a.s2;
#pragma unroll
      for (int j = 0; j < NF; ++j) {
        int n = bn0 + wc * 64 + j * 16 + lm;
        float v = acc[i][j][r];
        if constexpr (HASD) v += bf2f(Dp[db + n]);
        if constexpr (OF32) ((float*)O.p[z])[ob + n] = v;
        else ((unsigned short*)O.p[z])[ob + n] = (unsigned short)f2bf(v);
      }
    }
  }
}

// --- converts ----------------------------------------------------------------
__global__ void convert_x(const float* x, unsigned short* Xb) {  // 16.8M elems, 8/thread
  long i = ((long)blockIdx.x * 256 + threadIdx.x) * 8;
  float4v a = *(const float4v*)(x + i);
  float4v b = *(const float4v*)(x + i + 4);
  short8v s;
  s[0] = f2bf(a.x); s[1] = f2bf(a.y); s[2] = f2bf(a.z); s[3] = f2bf(a.w);
  s[4] = f2bf(b.x); s[5] = f2bf(b.y); s[6] = f2bf(b.z); s[7] = f2bf(b.w);
  *(short8v*)(Xb + i) = s;
}
__global__ void convert_wt(const float* W, unsigned short* Wt) {  // Wt[1024][512]
  int i = blockIdx.x * 256 + threadIdx.x;
  int n = i >> 9, k = i & 511;
  Wt[i] = (unsigned short)f2bf(W[(long)k * 1024 + n]);
}
__global__ void convert_rrm(const float* R, unsigned short* Rrm) {
  int i = blockIdx.x * 256 + threadIdx.x;
  Rrm[i] = (unsigned short)f2bf(R[i]);
}
__global__ void convert_rt(const float* R, unsigned short* Rt) {  // Rt[n][k]=R[k][n]
  int i = blockIdx.x * 256 + threadIdx.x;
  int n = i >> 10, k = i & 1023;
  Rt[i] = (unsigned short)f2bf(R[(long)k * 1024 + n]);
}

// --- host helpers ------------------------------------------------------------
static inline Op opS(const void* p, Addr a, long zs = 0) {
  Op o{}; for (int i = 0; i < 8; ++i) o.p[i] = p; o.a = a; o.zs = zs; return o;
}
static inline Addr contig(long base, long stride, int qmin = 0) {
  return Addr{base, stride, 0, 1, qmin};
}

template<bool OF32, bool HASD>
static inline void G(hipStream_t s, int M, int K, Op A, Op B, Op D, Op O,
                     const unsigned short* zbuf, int Z = 1) {
  dim3 grid(M / 64, 8, Z);
  hipLaunchKernelGGL((gemm_k<64, OF32, HASD>), grid, dim3(256), 0, s,
                     A, B, D, O, M, K, zbuf);
}

extern "C" void kernel_launch(void* const* d_in, const int* in_sizes, int n_in,
                              void* d_out, int out_size, void* d_ws, size_t ws_size,
                              hipStream_t stream) {
  (void)in_sizes; (void)n_in; (void)out_size; (void)ws_size;
  const float* x = (const float*)d_in[0];     // [32,1024,512]
  const float* W = (const float*)d_in[2];     // [512,1024]
  const float* R = (const float*)d_in[3];     // [1024,1024]
  float* out = (float*)d_out;                 // [32,1024,1024]

  char* ws = (char*)d_ws;
  size_t off = 0;
  auto alloc = [&](size_t bytes) { void* p = ws + off; off += bytes; return p; };
  unsigned short* zbuf = (unsigned short*)alloc(4096);            // >= K elems of zeros
  unsigned short* Wt = (unsigned short*)alloc(1024 * 512 * 2);
  auto mat = [&]() { return (unsigned short*)alloc(1024 * 1024 * 2); };
  unsigned short *Rt = mat(), *Rrm = mat();
  unsigned short *G2 = mat(), *R2 = mat(), *G3 = mat(), *G4 = mat(), *R4 = mat();
  unsigned short *G5 = mat(), *G6 = mat(), *G7 = mat(), *G8 = mat(), *R8 = mat();
  unsigned short *G16 = mat(), *R16 = mat(), *G32 = mat(), *R32 = mat();
  unsigned short *G64 = mat(), *R64 = mat(), *G128 = mat(), *R128 = mat();
  unsigned short *G256 = mat(), *R256 = mat(), *G512 = mat();
  unsigned short* XWL = (unsigned short*)alloc((size_t)32 * 1024 * 1024 * 2);  // [b][t][u] bf16
  unsigned short* S0  = (unsigned short*)alloc((size_t)4096 * 1024 * 2);       // [c*32+b][u]
  unsigned short* S1  = (unsigned short*)alloc((size_t)4096 * 1024 * 2);
  // Xb (bf16 x, 32 MB) lives in the head of d_out: read only by P0, and P3
  // overwrites the whole output at the end.
  unsigned short* Xb = (unsigned short*)d_out;

  const Addr nil{0, 0, 0, 1, 0};
  const Addr c1024{0, 1024, 0, 1, 0};

  hipMemsetAsync(zbuf, 0, 4096, stream);
  hipLaunchKernelGGL(convert_x,   dim3(8192), dim3(256), 0, stream, x, Xb);
  hipLaunchKernelGGL(convert_wt,  dim3(2048), dim3(256), 0, stream, W, Wt);
  hipLaunchKernelGGL(convert_rrm, dim3(4096), dim3(256), 0, stream, R, Rrm);
  hipLaunchKernelGGL(convert_rt,  dim3(4096), dim3(256), 0, stream, R, Rt);

  // power layers: O_z = A_z * B_z (Bt = transposed operand), z-batched
  auto PL = [&](int n, const unsigned short* const* Aa, const unsigned short* const* Bb,
                unsigned short* const* Oo) {
    Op A{}, B{}, D{}, O{};
    A.a = c1024; O.a = c1024; B.a = nil; D.a = nil;
    for (int i = 0; i < n; ++i) { A.p[i] = Aa[i]; B.p[i] = Bb[i]; O.p[i] = Oo[i]; }
    dim3 grid(1024 / 64, 8, n);
    hipLaunchKernelGGL((gemm_k<64, false, false>), grid, dim3(256), 0, stream,
                       A, B, D, O, 1024, 1024, zbuf);
  };
  { const unsigned short* Aa[] = {Rt, Rrm};                 const unsigned short* Bb[] = {Rrm, Rt};
    unsigned short* Oo[] = {G2, R2};                        PL(2, Aa, Bb, Oo); }
  { const unsigned short* Aa[] = {G2, R2, G2};              const unsigned short* Bb[] = {R2, G2, Rrm};
    unsigned short* Oo[] = {G4, R4, G3};                    PL(3, Aa, Bb, Oo); }
  { const unsigned short* Aa[] = {G4, R4, G4, G4, G3};      const unsigned short* Bb[] = {R4, G4, Rrm, R2, R4};
    unsigned short* Oo[] = {G8, R8, G5, G6, G7};            PL(5, Aa, Bb, Oo); }
  { const unsigned short* Aa[] = {G8, R8};                  const unsigned short* Bb[] = {R8, G8};
    unsigned short* Oo[] = {G16, R16};                      PL(2, Aa, Bb, Oo); }
  { const unsigned short* Aa[] = {G16, R16};                const unsigned short* Bb[] = {R16, G16};
    unsigned short* Oo[] = {G32, R32};                      PL(2, Aa, Bb, Oo); }
  { const unsigned short* Aa[] = {G32, R32};                const unsigned short* Bb[] = {R32, G32};
    unsigned short* Oo[] = {G64, R64};                      PL(2, Aa, Bb, Oo); }
  { const unsigned short* Aa[] = {G64, R64};                const unsigned short* Bb[] = {R64, G64};
    unsigned short* Oo[] = {G128, R128};                    PL(2, Aa, Bb, Oo); }
  { const unsigned short* Aa[] = {G128, R128};              const unsigned short* Bb[] = {R128, G128};
    unsigned short* Oo[] = {G256, R256};                    PL(2, Aa, Bb, Oo); }
  { const unsigned short* Aa[] = {G256};                    const unsigned short* Bb[] = {R256};
    unsigned short* Oo[] = {G512};                          PL(1, Aa, Bb, Oo); }

  // P0: XWL = Xb @ W (bf16 in, bf16 out), M=32768 K=512
  G<false, false>(stream, 32768, 512,
      opS(Xb, contig(0, 512)), opS(Wt, nil), opS(nullptr, nil), opS(XWL, c1024), zbuf);

  // P1: in-place local scans over slots j (rows m=c*32+b)
  for (int j = 1; j <= 7; ++j) {
    Addr prev{(long)(j - 1) * 1024, 8192, 1048576, 32, 0};
    Addr cur {(long)j * 1024, 8192, 1048576, 32, 0};
    G<false, true>(stream, 4096, 1024,
        opS(XWL, prev), opS(Rt, nil), opS(XWL, cur), opS(XWL, cur), zbuf);
  }

  // P2: Kogge-Stone inclusive scan of E_c with operator R^8 (7 steps, ping-pong)
  // s=0: S0[c] = E_c + E_{c-1} R^8   (E_c = XWL slot c*8+7)
  G<false, true>(stream, 4096, 1024,
      opS(XWL, Addr{7168 - 8192, 8192, 1048576, 32, 1}), opS(G8, nil),
      opS(XWL, Addr{7168, 8192, 1048576, 32, 0}), opS(S0, c1024), zbuf);
  { const unsigned short* ops[6] = {G16, G32, G64, G128, G256, G512};
    unsigned short* buf[2] = {S0, S1};
    for (int s = 1; s <= 6; ++s) {
      unsigned short* Sp = buf[(s + 1) & 1];   // s=1: S0 -> S1, s=2: S1 -> S0, ...
      unsigned short* Sn = buf[s & 1];
      G<false, true>(stream, 4096, 1024,
          opS(Sp, contig(-(32768L << s), 1024, 32 << s)), opS(ops[s - 1], nil),
          opS(Sp, c1024), opS(Sn, c1024), zbuf);
    }
  }
  // final inclusive scan in S0 (after s=6); carry into chunk c is S0[c-1]

  // P3: out[b][c*8+j] = L_j[c,b] + S_{c-1} @ R^{j+1}  (z=j, fp32 out)
  {
    Op B{}; B.a = nil;
    const unsigned short* gj[8] = {Rt, G2, G3, G4, G5, G6, G7, G8};
    for (int i = 0; i < 8; ++i) B.p[i] = gj[i];
    Addr slot{0, 8192, 1048576, 32, 0};
    G<true, true>(stream, 4096, 1024,
        opS(S0, contig(-32768, 1024, 32)), B,
        opS(XWL, slot, 1024), opS(out, slot, 1024), zbuf, 8);
  }
}

// Round 3
// 821.373 us; speedup vs baseline: 1.1467x; 1.0544x over previous
//
#include <hip/hip_runtime.h>

// MinimalRNNCell h_t = x_t W + h_{t-1} R.  B=32 T=1024 D=512 U=1024, out fp32.
// R6: 2-deep LDS pipeline (48KB -> 3 blocks/CU) + st-style XOR swizzle kept
// from R5 (inverse-swizzled GLOBAL source + swizzled ds_read: rule #21) +
// counted raw-barrier schedule + setprio around MFMA. Uniform BM=64.
//   C0: Xb = bf16(x)                       [elementwise]
//   P0: XW = Xb@W -> XWL (bf16)            [M=32768 K=512]
//   P1: in-place local scans slot j=1..7   [7 launches, M=4096]
//   P2: KS over 128 chunk carries          [7 launches, M=4096, ping-pong S0/S1]
//   P3: out = L_j + S_{c-1} R^{j+1}        [1 launch, z=8, fp32 out]

typedef __attribute__((ext_vector_type(4))) float  floatx4;
typedef __attribute__((ext_vector_type(4))) float  float4v;
typedef __attribute__((ext_vector_type(8))) short  short8v;

__device__ __forceinline__ short f2bf(float f) {  // RNE
  unsigned u = __float_as_uint(f);
  u += 0x7fffu + ((u >> 16) & 1u);
  return (short)(u >> 16);
}
__device__ __forceinline__ float bf2f(unsigned short u) {
  return __uint_as_float((unsigned)u << 16);
}
__device__ __forceinline__ void ld16(short* lds, const void* g) {  // async 16B global->LDS
  __builtin_amdgcn_global_load_lds((const __attribute__((address_space(1))) unsigned*)g,
                                   (__attribute__((address_space(3))) unsigned*)lds, 16, 0, 0);
}

#define WAITV0 asm volatile("s_waitcnt vmcnt(0)" ::: "memory")

// row m -> element offset base + z*zs + (m/div)*s1 + (m%div)*s2 ; row valid iff (m/div)>=qmin
struct Addr { long base, s1, s2; int div, qmin; };
struct Op { const void* p[8]; Addr a; long zs; };

// ---------------------------------------------------------------------------
// OUT[z][m,n] = (HASD ? D : 0) + A[m,:]*B  ; N=1024, BN=128, BK=64.
// A bf16 [m][K] via Addr, B bf16 [n][K], D bf16, OUT fp32/bf16.
// LDS layout: rows of 64 bf16 (8 slots x 16B); physical slot p of row r holds
// logical slot p ^ (r&7). Staged via linear-dest global_load_lds with the
// inverse swizzle baked into the per-lane GLOBAL address; ds_read applies the
// same XOR -> zero bank conflicts (verified R5).
// 2-deep pipeline (48KB LDS, 3 blocks/CU): stage(t+1) issued before compute(t)
// so the load latency hides under ds_read+MFMA; vmcnt(0)+s_barrier per tile;
// residual latency covered by 3-block TLP.
// ---------------------------------------------------------------------------
template<int BM, bool OF32, bool HASD>
__global__ __launch_bounds__(256) void gemm_k(Op A, Op B, Op D, Op O, int M, int K,
                                              const unsigned short* zbuf)
{
  constexpr int BK = 64;
  constexpr int MF = BM / 32;          // 16x16 m-frags per wave (WM=2)
  constexpr int NF = 4;                // n-frags per wave (WN=2)
  constexpr int ABR = BM / 32;         // A staging rounds (32 rows / round)

  __shared__ __align__(16) short As[2][BM * BK];
  __shared__ __align__(16) short Bs[2][128 * BK];

  const int tid  = threadIdx.x;
  const int lane = tid & 63;
  const int wave = tid >> 6;
  const int wr = wave >> 1, wc = wave & 1;
  const int lm  = lane & 15;
  const int e7  = lm & 7;              // row&7 for all fragment rows this lane reads
  const int grp = lane >> 4;           // 16B column group

  const int z   = blockIdx.z;
  const int bm0 = blockIdx.x * BM;
  const int bn0 = blockIdx.y * 128;

  const long abase = A.a.base + (long)z * A.zs;

  // swizzled source column (elements): physical slot tid%8 of LDS row (tid/8)
  // must hold logical slot (tid%8)^((tid/8)&7)
  const int sw = (((tid & 7) ^ ((tid >> 3) & 7)) << 3);

  // B staging pointers: 4 rounds x 32 rows, 8 lanes/row (16B each)
  const unsigned short* Bp = (const unsigned short*)B.p[z];
  const unsigned short* bgp[4];
#pragma unroll
  for (int r = 0; r < 4; ++r)
    bgp[r] = Bp + (long)(bn0 + r * 32 + tid / 8) * K + sw;

  // A staging pointers: ABR rounds x 32 rows; invalid rows read zbuf (zeros)
  const unsigned short* agp[ABR];
#pragma unroll
  for (int r = 0; r < ABR; ++r) {
    int m = bm0 + r * 32 + tid / 8;
    int q = m / A.a.div;
    long off = abase + (long)q * A.a.s1 + (long)(m % A.a.div) * A.a.s2 + sw;
    agp[r] = (q >= A.a.qmin) ? (const unsigned short*)A.p[z] + off
                             : zbuf + sw;   // zbuf covers K elems of zeros
  }

  floatx4 acc[MF][NF] = {};

  const int NT = K / BK;

  auto stage = [&](int buf, int kb) {
#pragma unroll
    for (int r = 0; r < ABR; ++r)
      ld16(&As[buf][r * 2048 + tid * 8], agp[r] + kb);
#pragma unroll
    for (int r = 0; r < 4; ++r)
      ld16(&Bs[buf][r * 2048 + tid * 8], bgp[r] + kb);
  };

  // prologue: fill buffer 0
  stage(0, 0);
  WAITV0;
  __builtin_amdgcn_s_barrier();

  int cur = 0;
  for (int t = 0; t < NT; ++t) {
    if (t + 1 < NT) stage(cur ^ 1, (t + 1) * BK);   // issued before compute: latency hides
#pragma unroll
    for (int ks = 0; ks < 2; ++ks) {
      short8v af[MF], bfr[NF];
#pragma unroll
      for (int i = 0; i < MF; ++i) {
        int ar = wr * MF * 16 + i * 16 + lm;
        int ps = ((((ks << 2) | grp) ^ e7) << 3);
        af[i] = *(const short8v*)&As[cur][ar * BK + ps];
      }
#pragma unroll
      for (int j = 0; j < NF; ++j) {
        int br = wc * 64 + j * 16 + lm;
        int ps = ((((ks << 2) | grp) ^ e7) << 3);
        bfr[j] = *(const short8v*)&Bs[cur][br * BK + ps];
      }
      __builtin_amdgcn_s_setprio(1);
#pragma unroll
      for (int i = 0; i < MF; ++i)
#pragma unroll
        for (int j = 0; j < NF; ++j)
          acc[i][j] = __builtin_amdgcn_mfma_f32_16x16x32_bf16(af[i], bfr[j], acc[i][j], 0, 0, 0);
      __builtin_amdgcn_s_setprio(0);
    }
    if (t + 1 < NT) {
      WAITV0;                          // own stage writes for t+1 landed
      __builtin_amdgcn_s_barrier();    // all waves done reading cur + writes visible
    }
    cur ^= 1;
  }

  const long obase = O.a.base + (long)z * O.zs;
  long dbase = 0; const unsigned short* Dp = nullptr;
  if constexpr (HASD) { dbase = D.a.base + (long)z * D.zs; Dp = (const unsigned short*)D.p[z]; }

#pragma unroll
  for (int i = 0; i < MF; ++i) {
#pragma unroll
    for (int r = 0; r < 4; ++r) {
      int m = bm0 + wr * MF * 16 + i * 16 + (lane >> 4) * 4 + r;  // C/D: row=(lane>>4)*4+reg
      long ob = obase + (long)(m / O.a.div) * O.a.s1 + (long)(m % O.a.div) * O.a.s2;
      long db = 0;
      if constexpr (HASD) db = dbase + (long)(m / D.a.div) * D.a.s1 + (long)(m % D.a.div) * D.a.s2;
#pragma unroll
      for (int j = 0; j < NF; ++j) {
        int n = bn0 + wc * 64 + j * 16 + lm;
        float v = acc[i][j][r];
        if constexpr (HASD) v += bf2f(Dp[db + n]);
        if constexpr (OF32) ((float*)O.p[z])[ob + n] = v;
        else ((unsigned short*)O.p[z])[ob + n] = (unsigned short)f2bf(v);
      }
    }
  }
}

// --- converts ----------------------------------------------------------------
__global__ void convert_x(const float* x, unsigned short* Xb) {  // 16.8M elems, 8/thread
  long i = ((long)blockIdx.x * 256 + threadIdx.x) * 8;
  float4v a = *(const float4v*)(x + i);
  float4v b = *(const float4v*)(x + i + 4);
  short8v s;
  s[0] = f2bf(a.x); s[1] = f2bf(a.y); s[2] = f2bf(a.z); s[3] = f2bf(a.w);
  s[4] = f2bf(b.x); s[5] = f2bf(b.y); s[6] = f2bf(b.z); s[7] = f2bf(b.w);
  *(short8v*)(Xb + i) = s;
}
__global__ void convert_wt(const float* W, unsigned short* Wt) {  // Wt[1024][512]
  int i = blockIdx.x * 256 + threadIdx.x;
  int n = i >> 9, k = i & 511;
  Wt[i] = (unsigned short)f2bf(W[(long)k * 1024 + n]);
}
__global__ void convert_rrm(const float* R, unsigned short* Rrm) {
  int i = blockIdx.x * 256 + threadIdx.x;
  Rrm[i] = (unsigned short)f2bf(R[i]);
}
__global__ void convert_rt(const float* R, unsigned short* Rt) {  // Rt[n][k]=R[k][n]
  int i = blockIdx.x * 256 + threadIdx.x;
  int n = i >> 10, k = i & 1023;
  Rt[i] = (unsigned short)f2bf(R[(long)k * 1024 + n]);
}

// --- host helpers ------------------------------------------------------------
static inline Op opS(const void* p, Addr a, long zs = 0) {
  Op o{}; for (int i = 0; i < 8; ++i) o.p[i] = p; o.a = a; o.zs = zs; return o;
}
static inline Addr contig(long base, long stride, int qmin = 0) {
  return Addr{base, stride, 0, 1, qmin};
}

template<bool OF32, bool HASD>
static inline void G(hipStream_t s, int M, int K, Op A, Op B, Op D, Op O,
                     const unsigned short* zbuf, int Z = 1) {
  dim3 grid(M / 64, 8, Z);
  hipLaunchKernelGGL((gemm_k<64, OF32, HASD>), grid, dim3(256), 0, s,
                     A, B, D, O, M, K, zbuf);
}

extern "C" void kernel_launch(void* const* d_in, const int* in_sizes, int n_in,
                              void* d_out, int out_size, void* d_ws, size_t ws_size,
                              hipStream_t stream) {
  (void)in_sizes; (void)n_in; (void)out_size; (void)ws_size;
  const float* x = (const float*)d_in[0];     // [32,1024,512]
  const float* W = (const float*)d_in[2];     // [512,1024]
  const float* R = (const float*)d_in[3];     // [1024,1024]
  float* out = (float*)d_out;                 // [32,1024,1024]

  char* ws = (char*)d_ws;
  size_t off = 0;
  auto alloc = [&](size_t bytes) { void* p = ws + off; off += bytes; return p; };
  unsigned short* zbuf = (unsigned short*)alloc(4096);            // >= K elems of zeros
  unsigned short* Wt = (unsigned short*)alloc(1024 * 512 * 2);
  auto mat = [&]() { return (unsigned short*)alloc(1024 * 1024 * 2); };
  unsigned short *Rt = mat(), *Rrm = mat();
  unsigned short *G2 = mat(), *R2 = mat(), *G3 = mat(), *G4 = mat(), *R4 = mat();
  unsigned short *G5 = mat(), *G6 = mat(), *G7 = mat(), *G8 = mat(), *R8 = mat();
  unsigned short *G16 = mat(), *R16 = mat(), *G32 = mat(), *R32 = mat();
  unsigned short *G64 = mat(), *R64 = mat(), *G128 = mat(), *R128 = mat();
  unsigned short *G256 = mat(), *R256 = mat(), *G512 = mat();
  unsigned short* XWL = (unsigned short*)alloc((size_t)32 * 1024 * 1024 * 2);  // [b][t][u] bf16
  unsigned short* S0  = (unsigned short*)alloc((size_t)4096 * 1024 * 2);       // [c*32+b][u]
  unsigned short* S1  = (unsigned short*)alloc((size_t)4096 * 1024 * 2);
  // Xb (bf16 x, 32 MB) lives in the head of d_out: read only by P0, and P3
  // overwrites the whole output at the end.
  unsigned short* Xb = (unsigned short*)d_out;

  const Addr nil{0, 0, 0, 1, 0};
  const Addr c1024{0, 1024, 0, 1, 0};

  hipMemsetAsync(zbuf, 0, 4096, stream);
  hipLaunchKernelGGL(convert_x,   dim3(8192), dim3(256), 0, stream, x, Xb);
  hipLaunchKernelGGL(convert_wt,  dim3(2048), dim3(256), 0, stream, W, Wt);
  hipLaunchKernelGGL(convert_rrm, dim3(4096), dim3(256), 0, stream, R, Rrm);
  hipLaunchKernelGGL(convert_rt,  dim3(4096), dim3(256), 0, stream, R, Rt);

  // power layers: O_z = A_z * B_z (Bt = transposed operand), z-batched
  auto PL = [&](int n, const unsigned short* const* Aa, const unsigned short* const* Bb,
                unsigned short* const* Oo) {
    Op A{}, B{}, D{}, O{};
    A.a = c1024; O.a = c1024; B.a = nil; D.a = nil;
    for (int i = 0; i < n; ++i) { A.p[i] = Aa[i]; B.p[i] = Bb[i]; O.p[i] = Oo[i]; }
    dim3 grid(1024 / 64, 8, n);
    hipLaunchKernelGGL((gemm_k<64, false, false>), grid, dim3(256), 0, stream,
                       A, B, D, O, 1024, 1024, zbuf);
  };
  { const unsigned short* Aa[] = {Rt, Rrm};                 const unsigned short* Bb[] = {Rrm, Rt};
    unsigned short* Oo[] = {G2, R2};                        PL(2, Aa, Bb, Oo); }
  { const unsigned short* Aa[] = {G2, R2, G2};              const unsigned short* Bb[] = {R2, G2, Rrm};
    unsigned short* Oo[] = {G4, R4, G3};                    PL(3, Aa, Bb, Oo); }
  { const unsigned short* Aa[] = {G4, R4, G4, G4, G3};      const unsigned short* Bb[] = {R4, G4, Rrm, R2, R4};
    unsigned short* Oo[] = {G8, R8, G5, G6, G7};            PL(5, Aa, Bb, Oo); }
  { const unsigned short* Aa[] = {G8, R8};                  const unsigned short* Bb[] = {R8, G8};
    unsigned short* Oo[] = {G16, R16};                      PL(2, Aa, Bb, Oo); }
  { const unsigned short* Aa[] = {G16, R16};                const unsigned short* Bb[] = {R16, G16};
    unsigned short* Oo[] = {G32, R32};                      PL(2, Aa, Bb, Oo); }
  { const unsigned short* Aa[] = {G32, R32};                const unsigned short* Bb[] = {R32, G32};
    unsigned short* Oo[] = {G64, R64};                      PL(2, Aa, Bb, Oo); }
  { const unsigned short* Aa[] = {G64, R64};                const unsigned short* Bb[] = {R64, G64};
    unsigned short* Oo[] = {G128, R128};                    PL(2, Aa, Bb, Oo); }
  { const unsigned short* Aa[] = {G128, R128};              const unsigned short* Bb[] = {R128, G128};
    unsigned short* Oo[] = {G256, R256};                    PL(2, Aa, Bb, Oo); }
  { const unsigned short* Aa[] = {G256};                    const unsigned short* Bb[] = {R256};
    unsigned short* Oo[] = {G512};                          PL(1, Aa, Bb, Oo); }

  // P0: XWL = Xb @ W (bf16 in, bf16 out), M=32768 K=512
  G<false, false>(stream, 32768, 512,
      opS(Xb, contig(0, 512)), opS(Wt, nil), opS(nullptr, nil), opS(XWL, c1024), zbuf);

  // P1: in-place local scans over slots j (rows m=c*32+b)
  for (int j = 1; j <= 7; ++j) {
    Addr prev{(long)(j - 1) * 1024, 8192, 1048576, 32, 0};
    Addr cur {(long)j * 1024, 8192, 1048576, 32, 0};
    G<false, true>(stream, 4096, 1024,
        opS(XWL, prev), opS(Rt, nil), opS(XWL, cur), opS(XWL, cur), zbuf);
  }

  // P2: Kogge-Stone inclusive scan of E_c with operator R^8 (7 steps, ping-pong)
  // s=0: S0[c] = E_c + E_{c-1} R^8   (E_c = XWL slot c*8+7)
  G<false, true>(stream, 4096, 1024,
      opS(XWL, Addr{7168 - 8192, 8192, 1048576, 32, 1}), opS(G8, nil),
      opS(XWL, Addr{7168, 8192, 1048576, 32, 0}), opS(S0, c1024), zbuf);
  { const unsigned short* ops[6] = {G16, G32, G64, G128, G256, G512};
    unsigned short* buf[2] = {S0, S1};
    for (int s = 1; s <= 6; ++s) {
      unsigned short* Sp = buf[(s + 1) & 1];   // s=1: S0 -> S1, s=2: S1 -> S0, ...
      unsigned short* Sn = buf[s & 1];
      G<false, true>(stream, 4096, 1024,
          opS(Sp, contig(-(32768L << s), 1024, 32 << s)), opS(ops[s - 1], nil),
          opS(Sp, c1024), opS(Sn, c1024), zbuf);
    }
  }
  // final inclusive scan in S0 (after s=6); carry into chunk c is S0[c-1]

  // P3: out[b][c*8+j] = L_j[c,b] + S_{c-1} @ R^{j+1}  (z=j, fp32 out)
  {
    Op B{}; B.a = nil;
    const unsigned short* gj[8] = {Rt, G2, G3, G4, G5, G6, G7, G8};
    for (int i = 0; i < 8; ++i) B.p[i] = gj[i];
    Addr slot{0, 8192, 1048576, 32, 0};
    G<true, true>(stream, 4096, 1024,
        opS(S0, contig(-32768, 1024, 32)), B,
        opS(XWL, slot, 1024), opS(out, slot, 1024), zbuf, 8);
  }
}

// Round 4
// 752.984 us; speedup vs baseline: 1.2509x; 1.0908x over previous
//
#include <hip/hip_runtime.h>

// MinimalRNNCell h_t = x_t W + h_{t-1} R.  B=32 T=1024 D=512 U=1024, out fp32.
// R7: per-phase tile shapes. gemm_k templated on <BM,BN> (4 waves, WM=WN=2):
//   P0/P3 : 128x128 (MF=NF=4, 32 MFMA : 16 ds_read/wave-tile, ~60% LDS ceiling)
//   P1/P2 : 64x64   (32KB LDS -> 4 blocks/CU, 50% occupancy, latency-bound)
//   PL    : 32x64   (grid-starved power-matrix chain, 2-4 blocks/CU)
// Keeps R5/R6 verified pieces: XOR swizzle via inverse-swizzled global source
// (0 bank conflicts), 2-deep stage-ahead + vmcnt(0)+s_barrier, setprio.
//   C0: Xb = bf16(x); P0: XW=Xb@W; P1 x7 local scans; P2 x7 KS; P3 apply (z=8)

typedef __attribute__((ext_vector_type(4))) float  floatx4;
typedef __attribute__((ext_vector_type(4))) float  float4v;
typedef __attribute__((ext_vector_type(8))) short  short8v;

__device__ __forceinline__ short f2bf(float f) {  // RNE
  unsigned u = __float_as_uint(f);
  u += 0x7fffu + ((u >> 16) & 1u);
  return (short)(u >> 16);
}
__device__ __forceinline__ float bf2f(unsigned short u) {
  return __uint_as_float((unsigned)u << 16);
}
__device__ __forceinline__ void ld16(short* lds, const void* g) {  // async 16B global->LDS
  __builtin_amdgcn_global_load_lds((const __attribute__((address_space(1))) unsigned*)g,
                                   (__attribute__((address_space(3))) unsigned*)lds, 16, 0, 0);
}

#define WAITV0 asm volatile("s_waitcnt vmcnt(0)" ::: "memory")

// row m -> element offset base + z*zs + (m/div)*s1 + (m%div)*s2 ; row valid iff (m/div)>=qmin
struct Addr { long base, s1, s2; int div, qmin; };
struct Op { const void* p[8]; Addr a; long zs; };

// ---------------------------------------------------------------------------
// OUT[z][m,n] = (HASD ? D : 0) + A[m,:]*B  ; N=1024, BK=64.
// A bf16 [m][K] via Addr, B bf16 [n][K], D bf16, OUT fp32/bf16.
// 4 waves as 2x2; wave tile = (BM/2) x (BN/2); MF=BM/32 NF=BN/32 16x16 frags.
// LDS rows of 64 bf16 = 8 x 16B slots; physical slot p of row r holds logical
// p ^ (r&7); staged via linear-dest global_load_lds with inverse swizzle baked
// into the per-lane GLOBAL address; ds_read applies the same XOR (0 conflicts,
// verified R5). 2-deep: stage(t+1) before compute(t); vmcnt(0)+s_barrier/tile.
// ---------------------------------------------------------------------------
template<int BM, int BN, bool OF32, bool HASD>
__global__ __launch_bounds__(256) void gemm_k(Op A, Op B, Op D, Op O, int M, int K,
                                              const unsigned short* zbuf)
{
  constexpr int BK  = 64;
  constexpr int MF  = BM / 32;         // m-frags per wave
  constexpr int NF  = BN / 32;         // n-frags per wave
  constexpr int ABR = BM / 32;         // A staging rounds (32 rows each)
  constexpr int BBR = BN / 32;         // B staging rounds

  __shared__ __align__(16) short As[2][BM * BK];
  __shared__ __align__(16) short Bs[2][BN * BK];

  const int tid  = threadIdx.x;
  const int lane = tid & 63;
  const int wave = tid >> 6;
  const int wr = wave >> 1, wc = wave & 1;
  const int lm  = lane & 15;
  const int e7  = lm & 7;              // row&7 for all fragment rows this lane reads
  const int grp = lane >> 4;           // 16B column group

  const int z   = blockIdx.z;
  const int bm0 = blockIdx.x * BM;
  const int bn0 = blockIdx.y * BN;

  const long abase = A.a.base + (long)z * A.zs;

  // swizzled source column (elements): physical slot tid%8 of LDS row (tid/8)
  // must hold logical slot (tid%8)^((tid/8)&7)
  const int sw = (((tid & 7) ^ ((tid >> 3) & 7)) << 3);

  // B staging pointers: BBR rounds x 32 rows, 8 lanes/row (16B each)
  const unsigned short* Bp = (const unsigned short*)B.p[z];
  const unsigned short* bgp[BBR];
#pragma unroll
  for (int r = 0; r < BBR; ++r)
    bgp[r] = Bp + (long)(bn0 + r * 32 + tid / 8) * K + sw;

  // A staging pointers: ABR rounds x 32 rows; invalid rows read zbuf (zeros)
  const unsigned short* agp[ABR];
#pragma unroll
  for (int r = 0; r < ABR; ++r) {
    int m = bm0 + r * 32 + tid / 8;
    int q = m / A.a.div;
    long off = abase + (long)q * A.a.s1 + (long)(m % A.a.div) * A.a.s2 + sw;
    agp[r] = (q >= A.a.qmin) ? (const unsigned short*)A.p[z] + off
                             : zbuf + sw;   // zbuf covers K elems of zeros
  }

  floatx4 acc[MF][NF] = {};

  const int NT = K / BK;

  auto stage = [&](int buf, int kb) {
#pragma unroll
    for (int r = 0; r < ABR; ++r)
      ld16(&As[buf][r * 2048 + tid * 8], agp[r] + kb);
#pragma unroll
    for (int r = 0; r < BBR; ++r)
      ld16(&Bs[buf][r * 2048 + tid * 8], bgp[r] + kb);
  };

  // prologue: fill buffer 0
  stage(0, 0);
  WAITV0;
  __builtin_amdgcn_s_barrier();

  int cur = 0;
  for (int t = 0; t < NT; ++t) {
    if (t + 1 < NT) stage(cur ^ 1, (t + 1) * BK);   // issued before compute: latency hides
#pragma unroll
    for (int ks = 0; ks < 2; ++ks) {
      short8v af[MF], bfr[NF];
      const int ps = ((((ks << 2) | grp) ^ e7) << 3);
#pragma unroll
      for (int i = 0; i < MF; ++i) {
        int ar = wr * MF * 16 + i * 16 + lm;
        af[i] = *(const short8v*)&As[cur][ar * BK + ps];
      }
#pragma unroll
      for (int j = 0; j < NF; ++j) {
        int br = wc * (BN / 2) + j * 16 + lm;
        bfr[j] = *(const short8v*)&Bs[cur][br * BK + ps];
      }
      __builtin_amdgcn_s_setprio(1);
#pragma unroll
      for (int i = 0; i < MF; ++i)
#pragma unroll
        for (int j = 0; j < NF; ++j)
          acc[i][j] = __builtin_amdgcn_mfma_f32_16x16x32_bf16(af[i], bfr[j], acc[i][j], 0, 0, 0);
      __builtin_amdgcn_s_setprio(0);
    }
    if (t + 1 < NT) {
      WAITV0;                          // own stage writes for t+1 landed
      __builtin_amdgcn_s_barrier();    // all waves done reading cur + writes visible
    }
    cur ^= 1;
  }

  const long obase = O.a.base + (long)z * O.zs;
  long dbase = 0; const unsigned short* Dp = nullptr;
  if constexpr (HASD) { dbase = D.a.base + (long)z * D.zs; Dp = (const unsigned short*)D.p[z]; }

#pragma unroll
  for (int i = 0; i < MF; ++i) {
#pragma unroll
    for (int r = 0; r < 4; ++r) {
      int m = bm0 + wr * MF * 16 + i * 16 + (lane >> 4) * 4 + r;  // C/D: row=(lane>>4)*4+reg
      long ob = obase + (long)(m / O.a.div) * O.a.s1 + (long)(m % O.a.div) * O.a.s2;
      long db = 0;
      if constexpr (HASD) db = dbase + (long)(m / D.a.div) * D.a.s1 + (long)(m % D.a.div) * D.a.s2;
#pragma unroll
      for (int j = 0; j < NF; ++j) {
        int n = bn0 + wc * (BN / 2) + j * 16 + lm;
        float v = acc[i][j][r];
        if constexpr (HASD) v += bf2f(Dp[db + n]);
        if constexpr (OF32) ((float*)O.p[z])[ob + n] = v;
        else ((unsigned short*)O.p[z])[ob + n] = (unsigned short)f2bf(v);
      }
    }
  }
}

// --- converts ----------------------------------------------------------------
__global__ void convert_x(const float* x, unsigned short* Xb) {  // 16.8M elems, 8/thread
  long i = ((long)blockIdx.x * 256 + threadIdx.x) * 8;
  float4v a = *(const float4v*)(x + i);
  float4v b = *(const float4v*)(x + i + 4);
  short8v s;
  s[0] = f2bf(a.x); s[1] = f2bf(a.y); s[2] = f2bf(a.z); s[3] = f2bf(a.w);
  s[4] = f2bf(b.x); s[5] = f2bf(b.y); s[6] = f2bf(b.z); s[7] = f2bf(b.w);
  *(short8v*)(Xb + i) = s;
}
__global__ void convert_wt(const float* W, unsigned short* Wt) {  // Wt[1024][512]
  int i = blockIdx.x * 256 + threadIdx.x;
  int n = i >> 9, k = i & 511;
  Wt[i] = (unsigned short)f2bf(W[(long)k * 1024 + n]);
}
__global__ void convert_rrm(const float* R, unsigned short* Rrm) {
  int i = blockIdx.x * 256 + threadIdx.x;
  Rrm[i] = (unsigned short)f2bf(R[i]);
}
__global__ void convert_rt(const float* R, unsigned short* Rt) {  // Rt[n][k]=R[k][n]
  int i = blockIdx.x * 256 + threadIdx.x;
  int n = i >> 10, k = i & 1023;
  Rt[i] = (unsigned short)f2bf(R[(long)k * 1024 + n]);
}

// --- host helpers ------------------------------------------------------------
static inline Op opS(const void* p, Addr a, long zs = 0) {
  Op o{}; for (int i = 0; i < 8; ++i) o.p[i] = p; o.a = a; o.zs = zs; return o;
}
static inline Addr contig(long base, long stride, int qmin = 0) {
  return Addr{base, stride, 0, 1, qmin};
}

template<int BM, int BN, bool OF32, bool HASD>
static inline void G(hipStream_t s, int M, int K, Op A, Op B, Op D, Op O,
                     const unsigned short* zbuf, int Z = 1) {
  dim3 grid(M / BM, 1024 / BN, Z);
  hipLaunchKernelGGL((gemm_k<BM, BN, OF32, HASD>), grid, dim3(256), 0, s,
                     A, B, D, O, M, K, zbuf);
}

extern "C" void kernel_launch(void* const* d_in, const int* in_sizes, int n_in,
                              void* d_out, int out_size, void* d_ws, size_t ws_size,
                              hipStream_t stream) {
  (void)in_sizes; (void)n_in; (void)out_size; (void)ws_size;
  const float* x = (const float*)d_in[0];     // [32,1024,512]
  const float* W = (const float*)d_in[2];     // [512,1024]
  const float* R = (const float*)d_in[3];     // [1024,1024]
  float* out = (float*)d_out;                 // [32,1024,1024]

  char* ws = (char*)d_ws;
  size_t off = 0;
  auto alloc = [&](size_t bytes) { void* p = ws + off; off += bytes; return p; };
  unsigned short* zbuf = (unsigned short*)alloc(4096);            // >= K elems of zeros
  unsigned short* Wt = (unsigned short*)alloc(1024 * 512 * 2);
  auto mat = [&]() { return (unsigned short*)alloc(1024 * 1024 * 2); };
  unsigned short *Rt = mat(), *Rrm = mat();
  unsigned short *G2 = mat(), *R2 = mat(), *G3 = mat(), *G4 = mat(), *R4 = mat();
  unsigned short *G5 = mat(), *G6 = mat(), *G7 = mat(), *G8 = mat(), *R8 = mat();
  unsigned short *G16 = mat(), *R16 = mat(), *G32 = mat(), *R32 = mat();
  unsigned short *G64 = mat(), *R64 = mat(), *G128 = mat(), *R128 = mat();
  unsigned short *G256 = mat(), *R256 = mat(), *G512 = mat();
  unsigned short* XWL = (unsigned short*)alloc((size_t)32 * 1024 * 1024 * 2);  // [b][t][u] bf16
  unsigned short* S0  = (unsigned short*)alloc((size_t)4096 * 1024 * 2);       // [c*32+b][u]
  unsigned short* S1  = (unsigned short*)alloc((size_t)4096 * 1024 * 2);
  // Xb (bf16 x, 32 MB) lives in the head of d_out: read only by P0, and P3
  // overwrites the whole output at the end.
  unsigned short* Xb = (unsigned short*)d_out;

  const Addr nil{0, 0, 0, 1, 0};
  const Addr c1024{0, 1024, 0, 1, 0};

  hipMemsetAsync(zbuf, 0, 4096, stream);
  hipLaunchKernelGGL(convert_x,   dim3(8192), dim3(256), 0, stream, x, Xb);
  hipLaunchKernelGGL(convert_wt,  dim3(2048), dim3(256), 0, stream, W, Wt);
  hipLaunchKernelGGL(convert_rrm, dim3(4096), dim3(256), 0, stream, R, Rrm);
  hipLaunchKernelGGL(convert_rt,  dim3(4096), dim3(256), 0, stream, R, Rt);

  // power layers: O_z = A_z * B_z (Bt = transposed operand), z-batched
  auto PL = [&](int n, const unsigned short* const* Aa, const unsigned short* const* Bb,
                unsigned short* const* Oo) {
    Op A{}, B{}, D{}, O{};
    A.a = c1024; O.a = c1024; B.a = nil; D.a = nil;
    for (int i = 0; i < n; ++i) { A.p[i] = Aa[i]; B.p[i] = Bb[i]; O.p[i] = Oo[i]; }
    G<32, 64, false, false>(stream, 1024, 1024, A, B, D, O, zbuf, n);
  };
  { const unsigned short* Aa[] = {Rt, Rrm};                 const unsigned short* Bb[] = {Rrm, Rt};
    unsigned short* Oo[] = {G2, R2};                        PL(2, Aa, Bb, Oo); }
  { const unsigned short* Aa[] = {G2, R2, G2};              const unsigned short* Bb[] = {R2, G2, Rrm};
    unsigned short* Oo[] = {G4, R4, G3};                    PL(3, Aa, Bb, Oo); }
  { const unsigned short* Aa[] = {G4, R4, G4, G4, G3};      const unsigned short* Bb[] = {R4, G4, Rrm, R2, R4};
    unsigned short* Oo[] = {G8, R8, G5, G6, G7};            PL(5, Aa, Bb, Oo); }
  { const unsigned short* Aa[] = {G8, R8};                  const unsigned short* Bb[] = {R8, G8};
    unsigned short* Oo[] = {G16, R16};                      PL(2, Aa, Bb, Oo); }
  { const unsigned short* Aa[] = {G16, R16};                const unsigned short* Bb[] = {R16, G16};
    unsigned short* Oo[] = {G32, R32};                      PL(2, Aa, Bb, Oo); }
  { const unsigned short* Aa[] = {G32, R32};                const unsigned short* Bb[] = {R32, G32};
    unsigned short* Oo[] = {G64, R64};                      PL(2, Aa, Bb, Oo); }
  { const unsigned short* Aa[] = {G64, R64};                const unsigned short* Bb[] = {R64, G64};
    unsigned short* Oo[] = {G128, R128};                    PL(2, Aa, Bb, Oo); }
  { const unsigned short* Aa[] = {G128, R128};              const unsigned short* Bb[] = {R128, G128};
    unsigned short* Oo[] = {G256, R256};                    PL(2, Aa, Bb, Oo); }
  { const unsigned short* Aa[] = {G256};                    const unsigned short* Bb[] = {R256};
    unsigned short* Oo[] = {G512};                          PL(1, Aa, Bb, Oo); }

  // P0: XWL = Xb @ W (bf16 in, bf16 out), M=32768 K=512
  G<128, 128, false, false>(stream, 32768, 512,
      opS(Xb, contig(0, 512)), opS(Wt, nil), opS(nullptr, nil), opS(XWL, c1024), zbuf);

  // P1: in-place local scans over slots j (rows m=c*32+b)
  for (int j = 1; j <= 7; ++j) {
    Addr prev{(long)(j - 1) * 1024, 8192, 1048576, 32, 0};
    Addr cur {(long)j * 1024, 8192, 1048576, 32, 0};
    G<64, 64, false, true>(stream, 4096, 1024,
        opS(XWL, prev), opS(Rt, nil), opS(XWL, cur), opS(XWL, cur), zbuf);
  }

  // P2: Kogge-Stone inclusive scan of E_c with operator R^8 (7 steps, ping-pong)
  // s=0: S0[c] = E_c + E_{c-1} R^8   (E_c = XWL slot c*8+7)
  G<64, 64, false, true>(stream, 4096, 1024,
      opS(XWL, Addr{7168 - 8192, 8192, 1048576, 32, 1}), opS(G8, nil),
      opS(XWL, Addr{7168, 8192, 1048576, 32, 0}), opS(S0, c1024), zbuf);
  { const unsigned short* ops[6] = {G16, G32, G64, G128, G256, G512};
    unsigned short* buf[2] = {S0, S1};
    for (int s = 1; s <= 6; ++s) {
      unsigned short* Sp = buf[(s + 1) & 1];   // s=1: S0 -> S1, s=2: S1 -> S0, ...
      unsigned short* Sn = buf[s & 1];
      G<64, 64, false, true>(stream, 4096, 1024,
          opS(Sp, contig(-(32768L << s), 1024, 32 << s)), opS(ops[s - 1], nil),
          opS(Sp, c1024), opS(Sn, c1024), zbuf);
    }
  }
  // final inclusive scan in S0 (after s=6); carry into chunk c is S0[c-1]

  // P3: out[b][c*8+j] = L_j[c,b] + S_{c-1} @ R^{j+1}  (z=j, fp32 out)
  {
    Op B{}; B.a = nil;
    const unsigned short* gj[8] = {Rt, G2, G3, G4, G5, G6, G7, G8};
    for (int i = 0; i < 8; ++i) B.p[i] = gj[i];
    Addr slot{0, 8192, 1048576, 32, 0};
    G<128, 128, true, true>(stream, 4096, 1024,
        opS(S0, contig(-32768, 1024, 32)), B,
        opS(XWL, slot, 1024), opS(out, slot, 1024), zbuf, 8);
  }
}

// Round 5
// 750.936 us; speedup vs baseline: 1.2543x; 1.0027x over previous
//
#include <hip/hip_runtime.h>

// MinimalRNNCell h_t = x_t W + h_{t-1} R.  B=32 T=1024 D=512 U=1024, out fp32.
// R8: SINGLE-buffered LDS (m97 2-barrier schedule) -> 32KB @128x128 tile ->
// up to 5 blocks/CU (was 2). R5-R7 evidence: every LDS increase cost blocks/CU
// and every occupancy gain beat pipeline depth; m97+m131-140 prove implicit
// wave overlap at >=3 blocks/CU replaces explicit double-buffering.
// Keeps verified pieces: XOR swizzle via inverse-swizzled global source
// (0 bank conflicts), vmcnt(0)+s_barrier, setprio, per-phase tile shapes:
//   P0/P3 : 128x128   P1/P2 : 64x64   PL : 32x64
//   C0: Xb = bf16(x); P0: XW=Xb@W; P1 x7 local scans; P2 x7 KS; P3 apply (z=8)

typedef __attribute__((ext_vector_type(4))) float  floatx4;
typedef __attribute__((ext_vector_type(4))) float  float4v;
typedef __attribute__((ext_vector_type(8))) short  short8v;

__device__ __forceinline__ short f2bf(float f) {  // RNE
  unsigned u = __float_as_uint(f);
  u += 0x7fffu + ((u >> 16) & 1u);
  return (short)(u >> 16);
}
__device__ __forceinline__ float bf2f(unsigned short u) {
  return __uint_as_float((unsigned)u << 16);
}
__device__ __forceinline__ void ld16(short* lds, const void* g) {  // async 16B global->LDS
  __builtin_amdgcn_global_load_lds((const __attribute__((address_space(1))) unsigned*)g,
                                   (__attribute__((address_space(3))) unsigned*)lds, 16, 0, 0);
}

#define WAITV0 asm volatile("s_waitcnt vmcnt(0)" ::: "memory")

// row m -> element offset base + z*zs + (m/div)*s1 + (m%div)*s2 ; row valid iff (m/div)>=qmin
struct Addr { long base, s1, s2; int div, qmin; };
struct Op { const void* p[8]; Addr a; long zs; };

// ---------------------------------------------------------------------------
// OUT[z][m,n] = (HASD ? D : 0) + A[m,:]*B  ; N=1024, BK=64.
// A bf16 [m][K] via Addr, B bf16 [n][K], D bf16, OUT fp32/bf16.
// 4 waves as 2x2; wave tile = (BM/2) x (BN/2); MF=BM/32 NF=BN/32 16x16 frags.
// LDS rows of 64 bf16 = 8 x 16B slots; physical slot p of row r holds logical
// p ^ (r&7); staged via linear-dest global_load_lds with inverse swizzle baked
// into the per-lane GLOBAL address; ds_read applies the same XOR (0 conflicts,
// verified R5). Single buffer, m97 schedule: stage -> vmcnt(0)+barrier ->
// compute -> barrier; cross-block TLP (3-5 blocks/CU) hides the drain.
// ---------------------------------------------------------------------------
template<int BM, int BN, bool OF32, bool HASD>
__global__ __launch_bounds__(256) void gemm_k(Op A, Op B, Op D, Op O, int M, int K,
                                              const unsigned short* zbuf)
{
  constexpr int BK  = 64;
  constexpr int MF  = BM / 32;         // m-frags per wave
  constexpr int NF  = BN / 32;         // n-frags per wave
  constexpr int ABR = BM / 32;         // A staging rounds (32 rows each)
  constexpr int BBR = BN / 32;         // B staging rounds

  __shared__ __align__(16) short As[BM * BK];
  __shared__ __align__(16) short Bs[BN * BK];

  const int tid  = threadIdx.x;
  const int lane = tid & 63;
  const int wave = tid >> 6;
  const int wr = wave >> 1, wc = wave & 1;
  const int lm  = lane & 15;
  const int e7  = lm & 7;              // row&7 for all fragment rows this lane reads
  const int grp = lane >> 4;           // 16B column group

  const int z   = blockIdx.z;
  const int bm0 = blockIdx.x * BM;
  const int bn0 = blockIdx.y * BN;

  const long abase = A.a.base + (long)z * A.zs;

  // swizzled source column (elements): physical slot tid%8 of LDS row (tid/8)
  // must hold logical slot (tid%8)^((tid/8)&7)
  const int sw = (((tid & 7) ^ ((tid >> 3) & 7)) << 3);

  // B staging pointers: BBR rounds x 32 rows, 8 lanes/row (16B each)
  const unsigned short* Bp = (const unsigned short*)B.p[z];
  const unsigned short* bgp[BBR];
#pragma unroll
  for (int r = 0; r < BBR; ++r)
    bgp[r] = Bp + (long)(bn0 + r * 32 + tid / 8) * K + sw;

  // A staging pointers: ABR rounds x 32 rows; invalid rows read zbuf (zeros)
  const unsigned short* agp[ABR];
#pragma unroll
  for (int r = 0; r < ABR; ++r) {
    int m = bm0 + r * 32 + tid / 8;
    int q = m / A.a.div;
    long off = abase + (long)q * A.a.s1 + (long)(m % A.a.div) * A.a.s2 + sw;
    agp[r] = (q >= A.a.qmin) ? (const unsigned short*)A.p[z] + off
                             : zbuf + sw;   // zbuf covers K elems of zeros
  }

  floatx4 acc[MF][NF] = {};

  const int NT = K / BK;

  auto stage = [&](int kb) {
#pragma unroll
    for (int r = 0; r < ABR; ++r)
      ld16(&As[r * 2048 + tid * 8], agp[r] + kb);
#pragma unroll
    for (int r = 0; r < BBR; ++r)
      ld16(&Bs[r * 2048 + tid * 8], bgp[r] + kb);
  };

  // m97 2-barrier schedule, single buffer
  stage(0);
  WAITV0;
  __builtin_amdgcn_s_barrier();

  for (int t = 0; t < NT; ++t) {
#pragma unroll
    for (int ks = 0; ks < 2; ++ks) {
      short8v af[MF], bfr[NF];
      const int ps = ((((ks << 2) | grp) ^ e7) << 3);
#pragma unroll
      for (int i = 0; i < MF; ++i) {
        int ar = wr * MF * 16 + i * 16 + lm;
        af[i] = *(const short8v*)&As[ar * BK + ps];
      }
#pragma unroll
      for (int j = 0; j < NF; ++j) {
        int br = wc * (BN / 2) + j * 16 + lm;
        bfr[j] = *(const short8v*)&Bs[br * BK + ps];
      }
      __builtin_amdgcn_s_setprio(1);
#pragma unroll
      for (int i = 0; i < MF; ++i)
#pragma unroll
        for (int j = 0; j < NF; ++j)
          acc[i][j] = __builtin_amdgcn_mfma_f32_16x16x32_bf16(af[i], bfr[j], acc[i][j], 0, 0, 0);
      __builtin_amdgcn_s_setprio(0);
    }
    if (t + 1 < NT) {
      __builtin_amdgcn_s_barrier();    // all waves finished reading this tile
      stage((t + 1) * BK);
      WAITV0;                          // own stage writes landed
      __builtin_amdgcn_s_barrier();    // all waves' writes visible
    }
  }

  const long obase = O.a.base + (long)z * O.zs;
  long dbase = 0; const unsigned short* Dp = nullptr;
  if constexpr (HASD) { dbase = D.a.base + (long)z * D.zs; Dp = (const unsigned short*)D.p[z]; }

#pragma unroll
  for (int i = 0; i < MF; ++i) {
#pragma unroll
    for (int r = 0; r < 4; ++r) {
      int m = bm0 + wr * MF * 16 + i * 16 + (lane >> 4) * 4 + r;  // C/D: row=(lane>>4)*4+reg
      long ob = obase + (long)(m / O.a.div) * O.a.s1 + (long)(m % O.a.div) * O.a.s2;
      long db = 0;
      if constexpr (HASD) db = dbase + (long)(m / D.a.div) * D.a.s1 + (long)(m % D.a.div) * D.a.s2;
#pragma unroll
      for (int j = 0; j < NF; ++j) {
        int n = bn0 + wc * (BN / 2) + j * 16 + lm;
        float v = acc[i][j][r];
        if constexpr (HASD) v += bf2f(Dp[db + n]);
        if constexpr (OF32) ((float*)O.p[z])[ob + n] = v;
        else ((unsigned short*)O.p[z])[ob + n] = (unsigned short)f2bf(v);
      }
    }
  }
}

// --- converts ----------------------------------------------------------------
__global__ void convert_x(const float* x, unsigned short* Xb) {  // 16.8M elems, 8/thread
  long i = ((long)blockIdx.x * 256 + threadIdx.x) * 8;
  float4v a = *(const float4v*)(x + i);
  float4v b = *(const float4v*)(x + i + 4);
  short8v s;
  s[0] = f2bf(a.x); s[1] = f2bf(a.y); s[2] = f2bf(a.z); s[3] = f2bf(a.w);
  s[4] = f2bf(b.x); s[5] = f2bf(b.y); s[6] = f2bf(b.z); s[7] = f2bf(b.w);
  *(short8v*)(Xb + i) = s;
}
__global__ void convert_wt(const float* W, unsigned short* Wt) {  // Wt[1024][512]
  int i = blockIdx.x * 256 + threadIdx.x;
  int n = i >> 9, k = i & 511;
  Wt[i] = (unsigned short)f2bf(W[(long)k * 1024 + n]);
}
__global__ void convert_rrm(const float* R, unsigned short* Rrm) {
  int i = blockIdx.x * 256 + threadIdx.x;
  Rrm[i] = (unsigned short)f2bf(R[i]);
}
__global__ void convert_rt(const float* R, unsigned short* Rt) {  // Rt[n][k]=R[k][n]
  int i = blockIdx.x * 256 + threadIdx.x;
  int n = i >> 10, k = i & 1023;
  Rt[i] = (unsigned short)f2bf(R[(long)k * 1024 + n]);
}

// --- host helpers ------------------------------------------------------------
static inline Op opS(const void* p, Addr a, long zs = 0) {
  Op o{}; for (int i = 0; i < 8; ++i) o.p[i] = p; o.a = a; o.zs = zs; return o;
}
static inline Addr contig(long base, long stride, int qmin = 0) {
  return Addr{base, stride, 0, 1, qmin};
}

template<int BM, int BN, bool OF32, bool HASD>
static inline void G(hipStream_t s, int M, int K, Op A, Op B, Op D, Op O,
                     const unsigned short* zbuf, int Z = 1) {
  dim3 grid(M / BM, 1024 / BN, Z);
  hipLaunchKernelGGL((gemm_k<BM, BN, OF32, HASD>), grid, dim3(256), 0, s,
                     A, B, D, O, M, K, zbuf);
}

extern "C" void kernel_launch(void* const* d_in, const int* in_sizes, int n_in,
                              void* d_out, int out_size, void* d_ws, size_t ws_size,
                              hipStream_t stream) {
  (void)in_sizes; (void)n_in; (void)out_size; (void)ws_size;
  const float* x = (const float*)d_in[0];     // [32,1024,512]
  const float* W = (const float*)d_in[2];     // [512,1024]
  const float* R = (const float*)d_in[3];     // [1024,1024]
  float* out = (float*)d_out;                 // [32,1024,1024]

  char* ws = (char*)d_ws;
  size_t off = 0;
  auto alloc = [&](size_t bytes) { void* p = ws + off; off += bytes; return p; };
  unsigned short* zbuf = (unsigned short*)alloc(4096);            // >= K elems of zeros
  unsigned short* Wt = (unsigned short*)alloc(1024 * 512 * 2);
  auto mat = [&]() { return (unsigned short*)alloc(1024 * 1024 * 2); };
  unsigned short *Rt = mat(), *Rrm = mat();
  unsigned short *G2 = mat(), *R2 = mat(), *G3 = mat(), *G4 = mat(), *R4 = mat();
  unsigned short *G5 = mat(), *G6 = mat(), *G7 = mat(), *G8 = mat(), *R8 = mat();
  unsigned short *G16 = mat(), *R16 = mat(), *G32 = mat(), *R32 = mat();
  unsigned short *G64 = mat(), *R64 = mat(), *G128 = mat(), *R128 = mat();
  unsigned short *G256 = mat(), *R256 = mat(), *G512 = mat();
  unsigned short* XWL = (unsigned short*)alloc((size_t)32 * 1024 * 1024 * 2);  // [b][t][u] bf16
  unsigned short* S0  = (unsigned short*)alloc((size_t)4096 * 1024 * 2);       // [c*32+b][u]
  unsigned short* S1  = (unsigned short*)alloc((size_t)4096 * 1024 * 2);
  // Xb (bf16 x, 32 MB) lives in the head of d_out: read only by P0, and P3
  // overwrites the whole output at the end.
  unsigned short* Xb = (unsigned short*)d_out;

  const Addr nil{0, 0, 0, 1, 0};
  const Addr c1024{0, 1024, 0, 1, 0};

  hipMemsetAsync(zbuf, 0, 4096, stream);
  hipLaunchKernelGGL(convert_x,   dim3(8192), dim3(256), 0, stream, x, Xb);
  hipLaunchKernelGGL(convert_wt,  dim3(2048), dim3(256), 0, stream, W, Wt);
  hipLaunchKernelGGL(convert_rrm, dim3(4096), dim3(256), 0, stream, R, Rrm);
  hipLaunchKernelGGL(convert_rt,  dim3(4096), dim3(256), 0, stream, R, Rt);

  // power layers: O_z = A_z * B_z (Bt = transposed operand), z-batched
  auto PL = [&](int n, const unsigned short* const* Aa, const unsigned short* const* Bb,
                unsigned short* const* Oo) {
    Op A{}, B{}, D{}, O{};
    A.a = c1024; O.a = c1024; B.a = nil; D.a = nil;
    for (int i = 0; i < n; ++i) { A.p[i] = Aa[i]; B.p[i] = Bb[i]; O.p[i] = Oo[i]; }
    G<32, 64, false, false>(stream, 1024, 1024, A, B, D, O, zbuf, n);
  };
  { const unsigned short* Aa[] = {Rt, Rrm};                 const unsigned short* Bb[] = {Rrm, Rt};
    unsigned short* Oo[] = {G2, R2};                        PL(2, Aa, Bb, Oo); }
  { const unsigned short* Aa[] = {G2, R2, G2};              const unsigned short* Bb[] = {R2, G2, Rrm};
    unsigned short* Oo[] = {G4, R4, G3};                    PL(3, Aa, Bb, Oo); }
  { const unsigned short* Aa[] = {G4, R4, G4, G4, G3};      const unsigned short* Bb[] = {R4, G4, Rrm, R2, R4};
    unsigned short* Oo[] = {G8, R8, G5, G6, G7};            PL(5, Aa, Bb, Oo); }
  { const unsigned short* Aa[] = {G8, R8};                  const unsigned short* Bb[] = {R8, G8};
    unsigned short* Oo[] = {G16, R16};                      PL(2, Aa, Bb, Oo); }
  { const unsigned short* Aa[] = {G16, R16};                const unsigned short* Bb[] = {R16, G16};
    unsigned short* Oo[] = {G32, R32};                      PL(2, Aa, Bb, Oo); }
  { const unsigned short* Aa[] = {G32, R32};                const unsigned short* Bb[] = {R32, G32};
    unsigned short* Oo[] = {G64, R64};                      PL(2, Aa, Bb, Oo); }
  { const unsigned short* Aa[] = {G64, R64};                const unsigned short* Bb[] = {R64, G64};
    unsigned short* Oo[] = {G128, R128};                    PL(2, Aa, Bb, Oo); }
  { const unsigned short* Aa[] = {G128, R128};              const unsigned short* Bb[] = {R128, G128};
    unsigned short* Oo[] = {G256, R256};                    PL(2, Aa, Bb, Oo); }
  { const unsigned short* Aa[] = {G256};                    const unsigned short* Bb[] = {R256};
    unsigned short* Oo[] = {G512};                          PL(1, Aa, Bb, Oo); }

  // P0: XWL = Xb @ W (bf16 in, bf16 out), M=32768 K=512
  G<128, 128, false, false>(stream, 32768, 512,
      opS(Xb, contig(0, 512)), opS(Wt, nil), opS(nullptr, nil), opS(XWL, c1024), zbuf);

  // P1: in-place local scans over slots j (rows m=c*32+b)
  for (int j = 1; j <= 7; ++j) {
    Addr prev{(long)(j - 1) * 1024, 8192, 1048576, 32, 0};
    Addr cur {(long)j * 1024, 8192, 1048576, 32, 0};
    G<64, 64, false, true>(stream, 4096, 1024,
        opS(XWL, prev), opS(Rt, nil), opS(XWL, cur), opS(XWL, cur), zbuf);
  }

  // P2: Kogge-Stone inclusive scan of E_c with operator R^8 (7 steps, ping-pong)
  // s=0: S0[c] = E_c + E_{c-1} R^8   (E_c = XWL slot c*8+7)
  G<64, 64, false, true>(stream, 4096, 1024,
      opS(XWL, Addr{7168 - 8192, 8192, 1048576, 32, 1}), opS(G8, nil),
      opS(XWL, Addr{7168, 8192, 1048576, 32, 0}), opS(S0, c1024), zbuf);
  { const unsigned short* ops[6] = {G16, G32, G64, G128, G256, G512};
    unsigned short* buf[2] = {S0, S1};
    for (int s = 1; s <= 6; ++s) {
      unsigned short* Sp = buf[(s + 1) & 1];   // s=1: S0 -> S1, s=2: S1 -> S0, ...
      unsigned short* Sn = buf[s & 1];
      G<64, 64, false, true>(stream, 4096, 1024,
          opS(Sp, contig(-(32768L << s), 1024, 32 << s)), opS(ops[s - 1], nil),
          opS(Sp, c1024), opS(Sn, c1024), zbuf);
    }
  }
  // final inclusive scan in S0 (after s=6); carry into chunk c is S0[c-1]

  // P3: out[b][c*8+j] = L_j[c,b] + S_{c-1} @ R^{j+1}  (z=j, fp32 out)
  {
    Op B{}; B.a = nil;
    const unsigned short* gj[8] = {Rt, G2, G3, G4, G5, G6, G7, G8};
    for (int i = 0; i < 8; ++i) B.p[i] = gj[i];
    Addr slot{0, 8192, 1048576, 32, 0};
    G<128, 128, true, true>(stream, 4096, 1024,
        opS(S0, contig(-32768, 1024, 32)), B,
        opS(XWL, slot, 1024), opS(out, slot, 1024), zbuf, 8);
  }
}

// Round 7
// 748.416 us; speedup vs baseline: 1.2585x; 1.0034x over previous
//
#include <hip/hip_runtime.h>

// MinimalRNNCell h_t = x_t W + h_{t-1} R.  B=32 T=1024 D=512 U=1024, out fp32.
// R9 (resubmit; prior attempt died to container-acquisition failure, no kernel
// signal). BK templated. P1/P2/PL (latency-bound mid/small grids) move to
// BK=128: halves the per-launch vmcnt(0)-drain count (NT 16->8) at unchanged 4
// blocks/CU (32KB LDS @64x64). P0/P3 stay BK=64 (128^2@BK=128 = 64KB LDS ->
// 2 blocks/CU, the m132 occupancy trap). Swizzle generalized to LPR=BK/8
// slots/row (stage-source XOR == read XOR on row&(LPR-1); bijective; residual
// 2-way aliasing free per m136). Keeps: single-buffer m97 2-barrier schedule,
// 0-conflict swizzle, setprio, per-phase tiles.
//   C0: Xb = bf16(x); P0: XW=Xb@W; P1 x7 local scans; P2 x7 KS; P3 apply (z=8)

typedef __attribute__((ext_vector_type(4))) float  floatx4;
typedef __attribute__((ext_vector_type(4))) float  float4v;
typedef __attribute__((ext_vector_type(8))) short  short8v;

__device__ __forceinline__ short f2bf(float f) {  // RNE
  unsigned u = __float_as_uint(f);
  u += 0x7fffu + ((u >> 16) & 1u);
  return (short)(u >> 16);
}
__device__ __forceinline__ float bf2f(unsigned short u) {
  return __uint_as_float((unsigned)u << 16);
}
__device__ __forceinline__ void ld16(short* lds, const void* g) {  // async 16B global->LDS
  __builtin_amdgcn_global_load_lds((const __attribute__((address_space(1))) unsigned*)g,
                                   (__attribute__((address_space(3))) unsigned*)lds, 16, 0, 0);
}

#define WAITV0 asm volatile("s_waitcnt vmcnt(0)" ::: "memory")

// row m -> element offset base + z*zs + (m/div)*s1 + (m%div)*s2 ; row valid iff (m/div)>=qmin
struct Addr { long base, s1, s2; int div, qmin; };
struct Op { const void* p[8]; Addr a; long zs; };

// ---------------------------------------------------------------------------
// OUT[z][m,n] = (HASD ? D : 0) + A[m,:]*B  ; N=1024.
// A bf16 [m][K] via Addr, B bf16 [n][K], D bf16, OUT fp32/bf16.
// 4 waves as 2x2; wave tile = (BM/2) x (BN/2); MF=BM/32 NF=BN/32 16x16 frags.
// LDS rows of BK bf16 = LPR x 16B slots; physical slot p of row r holds
// logical p ^ (r & (LPR-1)); staged via linear-dest global_load_lds with the
// inverse swizzle baked into the per-lane GLOBAL address; ds_read applies the
// same XOR (0 conflicts @BK=64 verified R5; BK=128 residual aliasing 2-way =
// free, m136). Single buffer, m97 schedule: stage -> vmcnt(0)+barrier ->
// compute -> barrier; cross-block TLP hides the drain.
// ---------------------------------------------------------------------------
template<int BM, int BN, int BK, bool OF32, bool HASD>
__global__ __launch_bounds__(256) void gemm_k(Op A, Op B, Op D, Op O, int M, int K,
                                              const unsigned short* zbuf)
{
  constexpr int LPR = BK / 8;          // 16B slots (lanes) per staged row
  constexpr int RPR = 256 / LPR;       // rows per staging round
  constexpr int ABR = BM / RPR;        // A staging rounds
  constexpr int BBR = BN / RPR;        // B staging rounds
  constexpr int KS  = BK / 32;         // MFMA k-steps per tile
  constexpr int MF  = BM / 32;         // m-frags per wave
  constexpr int NF  = BN / 32;         // n-frags per wave

  __shared__ __align__(16) short As[BM * BK];
  __shared__ __align__(16) short Bs[BN * BK];

  const int tid  = threadIdx.x;
  const int lane = tid & 63;
  const int wave = tid >> 6;
  const int wr = wave >> 1, wc = wave & 1;
  const int lm  = lane & 15;
  const int grp = lane >> 4;           // 16B column group

  const int z   = blockIdx.z;
  const int bm0 = blockIdx.x * BM;
  const int bn0 = blockIdx.y * BN;

  const long abase = A.a.base + (long)z * A.zs;

  // swizzled source column (elements): physical slot tid%LPR of LDS row
  // (tid/LPR) must hold logical slot (tid%LPR)^((tid/LPR)%LPR)
  const int sw = (((tid % LPR) ^ ((tid / LPR) % LPR)) << 3);

  // B staging pointers: BBR rounds x RPR rows, LPR lanes/row (16B each)
  const unsigned short* Bp = (const unsigned short*)B.p[z];
  const unsigned short* bgp[BBR];
#pragma unroll
  for (int r = 0; r < BBR; ++r)
    bgp[r] = Bp + (long)(bn0 + r * RPR + tid / LPR) * K + sw;

  // A staging pointers: ABR rounds x RPR rows; invalid rows read zbuf (zeros)
  const unsigned short* agp[ABR];
#pragma unroll
  for (int r = 0; r < ABR; ++r) {
    int m = bm0 + r * RPR + tid / LPR;
    int q = m / A.a.div;
    long off = abase + (long)q * A.a.s1 + (long)(m % A.a.div) * A.a.s2 + sw;
    agp[r] = (q >= A.a.qmin) ? (const unsigned short*)A.p[z] + off
                             : zbuf + sw;   // zbuf covers K elems of zeros
  }

  floatx4 acc[MF][NF] = {};

  const int NT = K / BK;

  auto stage = [&](int kb) {
#pragma unroll
    for (int r = 0; r < ABR; ++r)
      ld16(&As[r * 2048 + tid * 8], agp[r] + kb);
#pragma unroll
    for (int r = 0; r < BBR; ++r)
      ld16(&Bs[r * 2048 + tid * 8], bgp[r] + kb);
  };

  // m97 2-barrier schedule, single buffer
  stage(0);
  WAITV0;
  __builtin_amdgcn_s_barrier();

  for (int t = 0; t < NT; ++t) {
#pragma unroll
    for (int ks = 0; ks < KS; ++ks) {
      short8v af[MF], bfr[NF];
      const int ps = ((((ks << 2) | grp) ^ (lm & (LPR - 1))) << 3);
#pragma unroll
      for (int i = 0; i < MF; ++i) {
        int ar = wr * MF * 16 + i * 16 + lm;
        af[i] = *(const short8v*)&As[ar * BK + ps];
      }
#pragma unroll
      for (int j = 0; j < NF; ++j) {
        int br = wc * (BN / 2) + j * 16 + lm;
        bfr[j] = *(const short8v*)&Bs[br * BK + ps];
      }
      __builtin_amdgcn_s_setprio(1);
#pragma unroll
      for (int i = 0; i < MF; ++i)
#pragma unroll
        for (int j = 0; j < NF; ++j)
          acc[i][j] = __builtin_amdgcn_mfma_f32_16x16x32_bf16(af[i], bfr[j], acc[i][j], 0, 0, 0);
      __builtin_amdgcn_s_setprio(0);
    }
    if (t + 1 < NT) {
      __builtin_amdgcn_s_barrier();    // all waves finished reading this tile
      stage((t + 1) * BK);
      WAITV0;                          // own stage writes landed
      __builtin_amdgcn_s_barrier();    // all waves' writes visible
    }
  }

  const long obase = O.a.base + (long)z * O.zs;
  long dbase = 0; const unsigned short* Dp = nullptr;
  if constexpr (HASD) { dbase = D.a.base + (long)z * D.zs; Dp = (const unsigned short*)D.p[z]; }

#pragma unroll
  for (int i = 0; i < MF; ++i) {
#pragma unroll
    for (int r = 0; r < 4; ++r) {
      int m = bm0 + wr * MF * 16 + i * 16 + (lane >> 4) * 4 + r;  // C/D: row=(lane>>4)*4+reg
      long ob = obase + (long)(m / O.a.div) * O.a.s1 + (long)(m % O.a.div) * O.a.s2;
      long db = 0;
      if constexpr (HASD) db = dbase + (long)(m / D.a.div) * D.a.s1 + (long)(m % D.a.div) * D.a.s2;
#pragma unroll
      for (int j = 0; j < NF; ++j) {
        int n = bn0 + wc * (BN / 2) + j * 16 + lm;
        float v = acc[i][j][r];
        if constexpr (HASD) v += bf2f(Dp[db + n]);
        if constexpr (OF32) ((float*)O.p[z])[ob + n] = v;
        else ((unsigned short*)O.p[z])[ob + n] = (unsigned short)f2bf(v);
      }
    }
  }
}

// --- converts ----------------------------------------------------------------
__global__ void convert_x(const float* x, unsigned short* Xb) {  // 16.8M elems, 8/thread
  long i = ((long)blockIdx.x * 256 + threadIdx.x) * 8;
  float4v a = *(const float4v*)(x + i);
  float4v b = *(const float4v*)(x + i + 4);
  short8v s;
  s[0] = f2bf(a.x); s[1] = f2bf(a.y); s[2] = f2bf(a.z); s[3] = f2bf(a.w);
  s[4] = f2bf(b.x); s[5] = f2bf(b.y); s[6] = f2bf(b.z); s[7] = f2bf(b.w);
  *(short8v*)(Xb + i) = s;
}
__global__ void convert_wt(const float* W, unsigned short* Wt) {  // Wt[1024][512]
  int i = blockIdx.x * 256 + threadIdx.x;
  int n = i >> 9, k = i & 511;
  Wt[i] = (unsigned short)f2bf(W[(long)k * 1024 + n]);
}
__global__ void convert_rrm(const float* R, unsigned short* Rrm) {
  int i = blockIdx.x * 256 + threadIdx.x;
  Rrm[i] = (unsigned short)f2bf(R[i]);
}
__global__ void convert_rt(const float* R, unsigned short* Rt) {  // Rt[n][k]=R[k][n]
  int i = blockIdx.x * 256 + threadIdx.x;
  int n = i >> 10, k = i & 1023;
  Rt[i] = (unsigned short)f2bf(R[(long)k * 1024 + n]);
}

// --- host helpers ------------------------------------------------------------
static inline Op opS(const void* p, Addr a, long zs = 0) {
  Op o{}; for (int i = 0; i < 8; ++i) o.p[i] = p; o.a = a; o.zs = zs; return o;
}
static inline Addr contig(long base, long stride, int qmin = 0) {
  return Addr{base, stride, 0, 1, qmin};
}

template<int BM, int BN, int BK, bool OF32, bool HASD>
static inline void G(hipStream_t s, int M, int K, Op A, Op B, Op D, Op O,
                     const unsigned short* zbuf, int Z = 1) {
  dim3 grid(M / BM, 1024 / BN, Z);
  hipLaunchKernelGGL((gemm_k<BM, BN, BK, OF32, HASD>), grid, dim3(256), 0, s,
                     A, B, D, O, M, K, zbuf);
}

extern "C" void kernel_launch(void* const* d_in, const int* in_sizes, int n_in,
                              void* d_out, int out_size, void* d_ws, size_t ws_size,
                              hipStream_t stream) {
  (void)in_sizes; (void)n_in; (void)out_size; (void)ws_size;
  const float* x = (const float*)d_in[0];     // [32,1024,512]
  const float* W = (const float*)d_in[2];     // [512,1024]
  const float* R = (const float*)d_in[3];     // [1024,1024]
  float* out = (float*)d_out;                 // [32,1024,1024]

  char* ws = (char*)d_ws;
  size_t off = 0;
  auto alloc = [&](size_t bytes) { void* p = ws + off; off += bytes; return p; };
  unsigned short* zbuf = (unsigned short*)alloc(4096);            // >= K elems of zeros
  unsigned short* Wt = (unsigned short*)alloc(1024 * 512 * 2);
  auto mat = [&]() { return (unsigned short*)alloc(1024 * 1024 * 2); };
  unsigned short *Rt = mat(), *Rrm = mat();
  unsigned short *G2 = mat(), *R2 = mat(), *G3 = mat(), *G4 = mat(), *R4 = mat();
  unsigned short *G5 = mat(), *G6 = mat(), *G7 = mat(), *G8 = mat(), *R8 = mat();
  unsigned short *G16 = mat(), *R16 = mat(), *G32 = mat(), *R32 = mat();
  unsigned short *G64 = mat(), *R64 = mat(), *G128 = mat(), *R128 = mat();
  unsigned short *G256 = mat(), *R256 = mat(), *G512 = mat();
  unsigned short* XWL = (unsigned short*)alloc((size_t)32 * 1024 * 1024 * 2);  // [b][t][u] bf16
  unsigned short* S0  = (unsigned short*)alloc((size_t)4096 * 1024 * 2);       // [c*32+b][u]
  unsigned short* S1  = (unsigned short*)alloc((size_t)4096 * 1024 * 2);
  // Xb (bf16 x, 32 MB) lives in the head of d_out: read only by P0, and P3
  // overwrites the whole output at the end.
  unsigned short* Xb = (unsigned short*)d_out;

  const Addr nil{0, 0, 0, 1, 0};
  const Addr c1024{0, 1024, 0, 1, 0};

  hipMemsetAsync(zbuf, 0, 4096, stream);
  hipLaunchKernelGGL(convert_x,   dim3(8192), dim3(256), 0, stream, x, Xb);
  hipLaunchKernelGGL(convert_wt,  dim3(2048), dim3(256), 0, stream, W, Wt);
  hipLaunchKernelGGL(convert_rrm, dim3(4096), dim3(256), 0, stream, R, Rrm);
  hipLaunchKernelGGL(convert_rt,  dim3(4096), dim3(256), 0, stream, R, Rt);

  // power layers: O_z = A_z * B_z (Bt = transposed operand), z-batched
  auto PL = [&](int n, const unsigned short* const* Aa, const unsigned short* const* Bb,
                unsigned short* const* Oo) {
    Op A{}, B{}, D{}, O{};
    A.a = c1024; O.a = c1024; B.a = nil; D.a = nil;
    for (int i = 0; i < n; ++i) { A.p[i] = Aa[i]; B.p[i] = Bb[i]; O.p[i] = Oo[i]; }
    G<32, 64, 128, false, false>(stream, 1024, 1024, A, B, D, O, zbuf, n);
  };
  { const unsigned short* Aa[] = {Rt, Rrm};                 const unsigned short* Bb[] = {Rrm, Rt};
    unsigned short* Oo[] = {G2, R2};                        PL(2, Aa, Bb, Oo); }
  { const unsigned short* Aa[] = {G2, R2, G2};              const unsigned short* Bb[] = {R2, G2, Rrm};
    unsigned short* Oo[] = {G4, R4, G3};                    PL(3, Aa, Bb, Oo); }
  { const unsigned short* Aa[] = {G4, R4, G4, G4, G3};      const unsigned short* Bb[] = {R4, G4, Rrm, R2, R4};
    unsigned short* Oo[] = {G8, R8, G5, G6, G7};            PL(5, Aa, Bb, Oo); }
  { const unsigned short* Aa[] = {G8, R8};                  const unsigned short* Bb[] = {R8, G8};
    unsigned short* Oo[] = {G16, R16};                      PL(2, Aa, Bb, Oo); }
  { const unsigned short* Aa[] = {G16, R16};                const unsigned short* Bb[] = {R16, G16};
    unsigned short* Oo[] = {G32, R32};                      PL(2, Aa, Bb, Oo); }
  { const unsigned short* Aa[] = {G32, R32};                const unsigned short* Bb[] = {R32, G32};
    unsigned short* Oo[] = {G64, R64};                      PL(2, Aa, Bb, Oo); }
  { const unsigned short* Aa[] = {G64, R64};                const unsigned short* Bb[] = {R64, G64};
    unsigned short* Oo[] = {G128, R128};                    PL(2, Aa, Bb, Oo); }
  { const unsigned short* Aa[] = {G128, R128};              const unsigned short* Bb[] = {R128, G128};
    unsigned short* Oo[] = {G256, R256};                    PL(2, Aa, Bb, Oo); }
  { const unsigned short* Aa[] = {G256};                    const unsigned short* Bb[] = {R256};
    unsigned short* Oo[] = {G512};                          PL(1, Aa, Bb, Oo); }

  // P0: XWL = Xb @ W (bf16 in, bf16 out), M=32768 K=512
  G<128, 128, 64, false, false>(stream, 32768, 512,
      opS(Xb, contig(0, 512)), opS(Wt, nil), opS(nullptr, nil), opS(XWL, c1024), zbuf);

  // P1: in-place local scans over slots j (rows m=c*32+b)
  for (int j = 1; j <= 7; ++j) {
    Addr prev{(long)(j - 1) * 1024, 8192, 1048576, 32, 0};
    Addr cur {(long)j * 1024, 8192, 1048576, 32, 0};
    G<64, 64, 128, false, true>(stream, 4096, 1024,
        opS(XWL, prev), opS(Rt, nil), opS(XWL, cur), opS(XWL, cur), zbuf);
  }

  // P2: Kogge-Stone inclusive scan of E_c with operator R^8 (7 steps, ping-pong)
  // s=0: S0[c] = E_c + E_{c-1} R^8   (E_c = XWL slot c*8+7)
  G<64, 64, 128, false, true>(stream, 4096, 1024,
      opS(XWL, Addr{7168 - 8192, 8192, 1048576, 32, 1}), opS(G8, nil),
      opS(XWL, Addr{7168, 8192, 1048576, 32, 0}), opS(S0, c1024), zbuf);
  { const unsigned short* ops[6] = {G16, G32, G64, G128, G256, G512};
    unsigned short* buf[2] = {S0, S1};
    for (int s = 1; s <= 6; ++s) {
      unsigned short* Sp = buf[(s + 1) & 1];   // s=1: S0 -> S1, s=2: S1 -> S0, ...
      unsigned short* Sn = buf[s & 1];
      G<64, 64, 128, false, true>(stream, 4096, 1024,
          opS(Sp, contig(-(32768L << s), 1024, 32 << s)), opS(ops[s - 1], nil),
          opS(Sp, c1024), opS(Sn, c1024), zbuf);
    }
  }
  // final inclusive scan in S0 (after s=6); carry into chunk c is S0[c-1]

  // P3: out[b][c*8+j] = L_j[c,b] + S_{c-1} @ R^{j+1}  (z=j, fp32 out)
  {
    Op B{}; B.a = nil;
    const unsigned short* gj[8] = {Rt, G2, G3, G4, G5, G6, G7, G8};
    for (int i = 0; i < 8; ++i) B.p[i] = gj[i];
    Addr slot{0, 8192, 1048576, 32, 0};
    G<128, 128, 64, true, true>(stream, 4096, 1024,
        opS(S0, contig(-32768, 1024, 32)), B,
        opS(XWL, slot, 1024), opS(out, slot, 1024), zbuf, 8);
  }
}